// Round 13
// baseline (2137.032 us; speedup 1.0000x reference)
//
#include <hip/hip_runtime.h>
#include <math.h>

#define N_NODES 250000
#define N_EDGES 2500000
#define N_GRAPHS 512
#define BN_EPS 1e-5f
#define NT 500000   // 2*N_NODES degree/offset slots (F then B)
#define INV_N (1.0f / (float)N_NODES)

// ================= CSR build (per call; ws is re-poisoned every launch) =====

__global__ void k_deg(const int* __restrict__ src, const int* __restrict__ dst,
                      int* __restrict__ deg, int E)
{
    int e = blockIdx.x * blockDim.x + threadIdx.x;
    if (e >= E) return;
    atomicAdd(&deg[dst[e]], 1);            // F lists keyed by dst
    atomicAdd(&deg[N_NODES + src[e]], 1);  // B lists keyed by src
}

__global__ void scan1(const int* __restrict__ deg, int* __restrict__ excl,
                      int* __restrict__ bsum, int n)
{
    __shared__ int s[256];
    int t = threadIdx.x, b = blockIdx.x;
    int base = b * 1024 + t * 4;
    int v[4]; int tsum = 0;
    #pragma unroll
    for (int i = 0; i < 4; i++) { v[i] = (base + i < n) ? deg[base + i] : 0; tsum += v[i]; }
    s[t] = tsum; __syncthreads();
    for (int o = 1; o < 256; o <<= 1) {
        int x = (t >= o) ? s[t - o] : 0; __syncthreads();
        s[t] += x; __syncthreads();
    }
    int run = s[t] - tsum;
    #pragma unroll
    for (int i = 0; i < 4; i++) { if (base + i < n) excl[base + i] = run; run += v[i]; }
    if (t == 255) bsum[b] = s[255];
}

__global__ void scan2(const int* __restrict__ bsum, int* __restrict__ boff, int nb)
{
    __shared__ int s[512];
    int t = threadIdx.x;
    int v = (t < nb) ? bsum[t] : 0;
    s[t] = v; __syncthreads();
    for (int o = 1; o < 512; o <<= 1) {
        int x = (t >= o) ? s[t - o] : 0; __syncthreads();
        s[t] += x; __syncthreads();
    }
    if (t < nb) boff[t] = s[t] - v;
}

__global__ void scan3(const int* __restrict__ excl, const int* __restrict__ boff,
                      int* __restrict__ off, int n)
{
    int i = blockIdx.x * blockDim.x + threadIdx.x;
    if (i < n) off[i] = excl[i] + boff[i >> 10];
    if (i == 0) off[n] = 2 * N_EDGES;
}

__global__ void k_fill(const int* __restrict__ src, const int* __restrict__ dst,
                       const int* __restrict__ off, int* __restrict__ cur,
                       int* __restrict__ eidx, int E)
{
    int e = blockIdx.x * blockDim.x + threadIdx.x;
    if (e >= E) return;
    int s = src[e], d = dst[e];
    int pF = atomicAdd(&cur[d], 1);
    eidx[off[d] + pF] = s;
    int pB = atomicAdd(&cur[N_NODES + s], 1);
    eidx[off[N_NODES + s] + pB] = d;
}

// ================= SPLIT PATH ===============================================
// gather_nbr: pure neighbor-sum, both directions per node, interleaved record
// agg[node*2D + dir*D + f]. THIS is the bottleneck kernel (~500us/layer,
// FETCH ~913 MB = 5M random 128B rows + eidx, near-compulsory; R11/R12
// counter rows labeled "dgin_mlp" are physically this kernel — the streaming
// mlp cannot fetch 913 MB). R12 state: VGPR 64 -> 4 waves/SIMD, occ 46%,
// VALU 8.5% -> concurrency-limited. gfx950 allocator law (measured R4-R10):
// VGPR cap = 256/declared-waves-per-EU. Declare (256,6) -> cap ~42; the pure
// gather's live set should fit -> 6 waves/EU = +50% outstanding misses.
// WATCH: if WRITE_SIZE balloons vs ~265 MB, it spilled -> revert to (256,4).

template <int DIN>
__global__ __launch_bounds__(256, 6)
void gather_nbr(const float* __restrict__ xin, const int* __restrict__ off,
                const int* __restrict__ eidx, float* __restrict__ agg, int ngroups)
{
    int tid = threadIdx.x;
    int f = tid & 31, hw = tid >> 5;
    for (int grp = blockIdx.x; grp < ngroups; grp += gridDim.x) {
        int node = grp * 8 + hw;
        #pragma unroll
        for (int dir = 0; dir < 2; dir++) {
            int u = dir * N_NODES + node;
            int k0 = off[u], k1 = off[u + 1];
            float r0 = 0.f, r1 = 0.f, r2 = 0.f, r3 = 0.f;
            for (int p = k0; p < k1; p += 8) {
                #pragma unroll
                for (int q = 0; q < 8; q++) {
                    int kk = p + q;
                    bool act = (kk < k1);
                    int j = eidx[act ? kk : k0];
                    float v;
                    if (DIN == 32) v = xin[j * 32 + f];
                    else           v = (f < DIN) ? xin[j * DIN + f] : 0.f;
                    v = act ? v : 0.f;
                    if ((q & 3) == 0)      r0 += v;
                    else if ((q & 3) == 1) r1 += v;
                    else if ((q & 3) == 2) r2 += v;
                    else                   r3 += v;
                }
            }
            float s = (r0 + r1) + (r2 + r3);
            if (DIN == 32)      agg[node * 64 + dir * 32 + f] = s;
            else if (f < DIN)   agg[node * (2 * DIN) + dir * DIN + f] = s;
        }
    }
}

// dgin_mlp: streaming (coalesced) dual-direction GIN MLP + BN stats.
// Reads self row + interleaved agg record + degrees; writes h IN PLACE.
// Prev layer's BN folded algebraically:
//   sum over (deg+1) rows of (a*v+b) = a*raw_sum + (deg+1)*b.

template <int DIN, bool BN_IN>
__global__ __launch_bounds__(256, 4)
void dgin_mlp(const float* __restrict__ xin, const float* __restrict__ agg,
              const int* __restrict__ off,
              const float* __restrict__ in_stats,
              const float* __restrict__ in_g, const float* __restrict__ in_b,
              const float* __restrict__ W1f, const float* __restrict__ b1f,
              const float* __restrict__ W2f, const float* __restrict__ b2f,
              const float* __restrict__ W1b, const float* __restrict__ b1b,
              const float* __restrict__ W2b, const float* __restrict__ b2b,
              float* __restrict__ out, float* __restrict__ stats, int ngroups)
{
    __shared__ float sW1[2][DIN * 32];
    __shared__ float sW2[2][32 * 32];
    __shared__ float sb1[2][32], sb2[2][32];
    __shared__ float sstat[64];

    int tid = threadIdx.x;
    for (int i = tid; i < DIN * 32; i += 256) { sW1[0][i] = W1f[i]; sW1[1][i] = W1b[i]; }
    for (int i = tid; i < 32 * 32;  i += 256) { sW2[0][i] = W2f[i]; sW2[1][i] = W2b[i]; }
    if (tid < 32) { sb1[0][tid] = b1f[tid]; sb1[1][tid] = b1b[tid];
                    sb2[0][tid] = b2f[tid]; sb2[1][tid] = b2b[tid]; }
    if (tid < 64) sstat[tid] = 0.f;
    __syncthreads();

    int f  = tid & 31;
    int hw = tid >> 5;

    float scale = 1.f, shift = 0.f;
    if (BN_IN) {
        float mu  = in_stats[f] * INV_N;
        float var = in_stats[32 + f] * INV_N - mu * mu;
        scale = in_g[f] * rsqrtf(var + BN_EPS);
        shift = in_b[f] - mu * scale;
    }

    float bn_s = 0.f, bn_s2 = 0.f;

    for (int grp = blockIdx.x; grp < ngroups; grp += gridDim.x) {
        int node = grp * 8 + hw;

        float xr, aF, aB;
        if (DIN == 32) {
            xr = xin[node * 32 + f];
            aF = agg[node * 64 + f];
            aB = agg[node * 64 + 32 + f];
        } else {
            xr = (f < DIN) ? xin[node * DIN + f] : 0.f;
            aF = (f < DIN) ? agg[node * (2 * DIN) + f] : 0.f;
            aB = (f < DIN) ? agg[node * (2 * DIN) + DIN + f] : 0.f;
        }
        int degF = off[node + 1] - off[node];
        int degB = off[N_NODES + node + 1] - off[N_NODES + node];

        float rawF = xr + aF;
        float rawB = xr + aB;
        float hinF = BN_IN ? fmaf(scale, rawF, (float)(degF + 1) * shift) : rawF;
        float hinB = BN_IN ? fmaf(scale, rawB, (float)(degB + 1) * shift) : rawB;

        float o = 0.f;
        #pragma unroll
        for (int dir = 0; dir < 2; dir++) {
            float hin = (dir == 0) ? hinF : hinB;

            float t1 = sb1[dir][f];
            #pragma unroll
            for (int i = 0; i < DIN; i++)
                t1 = fmaf(__shfl(hin, i, 32), sW1[dir][i * 32 + f], t1);
            t1 = fmaxf(t1, 0.f);

            float o2 = sb2[dir][f];
            #pragma unroll
            for (int i = 0; i < 32; i++)
                o2 = fmaf(__shfl(t1, i, 32), sW2[dir][i * 32 + f], o2);
            o += fmaxf(o2, 0.f);
        }
        o *= 0.5f;

        out[node * 32 + f] = o;
        bn_s  += o;
        bn_s2 += o * o;
    }

    atomicAdd(&sstat[f],      bn_s);
    atomicAdd(&sstat[32 + f], bn_s2);
    __syncthreads();
    if (tid < 64) atomicAdd(&stats[tid], sstat[tid]);
}

// ================= FUSED PATH (R10 fallback, used if ws too small) ==========

template <int DIN, bool BN_IN>
__global__ __launch_bounds__(256, 2)
void dgin_gather(const float* __restrict__ xin,
                 const int* __restrict__ off, const int* __restrict__ eidx,
                 const float* __restrict__ in_stats,
                 const float* __restrict__ in_g, const float* __restrict__ in_b,
                 const float* __restrict__ W1f, const float* __restrict__ b1f,
                 const float* __restrict__ W2f, const float* __restrict__ b2f,
                 const float* __restrict__ W1b, const float* __restrict__ b1b,
                 const float* __restrict__ W2b, const float* __restrict__ b2b,
                 float* __restrict__ out, float* __restrict__ stats, int ngroups)
{
    __shared__ float sW1[2][DIN * 32];
    __shared__ float sW2[2][32 * 32];
    __shared__ float sb1[2][32], sb2[2][32];
    __shared__ float sstat[64];

    int tid = threadIdx.x;
    for (int i = tid; i < DIN * 32; i += 256) { sW1[0][i] = W1f[i]; sW1[1][i] = W1b[i]; }
    for (int i = tid; i < 32 * 32;  i += 256) { sW2[0][i] = W2f[i]; sW2[1][i] = W2b[i]; }
    if (tid < 32) { sb1[0][tid] = b1f[tid]; sb1[1][tid] = b1b[tid];
                    sb2[0][tid] = b2f[tid]; sb2[1][tid] = b2b[tid]; }
    if (tid < 64) sstat[tid] = 0.f;
    __syncthreads();

    int f  = tid & 31;
    int hw = tid >> 5;

    float scale = 1.f, shift = 0.f;
    if (BN_IN) {
        float mu  = in_stats[f] * INV_N;
        float var = in_stats[32 + f] * INV_N - mu * mu;
        scale = in_g[f] * rsqrtf(var + BN_EPS);
        shift = in_b[f] - mu * scale;
    }

    float bn_s = 0.f, bn_s2 = 0.f;

    for (int grp = blockIdx.x; grp < ngroups; grp += gridDim.x) {
        int node = grp * 8 + hw;

        float xr = (DIN == 32) ? xin[node * 32 + f]
                               : ((f < DIN) ? xin[node * DIN + f] : 0.f);

        int k0F = off[node],           k1F = off[node + 1];
        int k0B = off[N_NODES + node], k1B = off[N_NODES + node + 1];
        int degF = k1F - k0F, degB = k1B - k0B;
        int tot  = degF + degB;

        float rF0 = 0.f, rF1 = 0.f, rF2 = 0.f, rF3 = 0.f;
        float rB0 = 0.f, rB1 = 0.f, rB2 = 0.f, rB3 = 0.f;
        for (int p = 0; p < tot; p += 8) {
            #pragma unroll
            for (int u = 0; u < 8; u++) {
                int q = p + u;
                bool act = (q < tot);
                bool isF = (q < degF);
                int kk = act ? (isF ? (k0F + q) : (k0B + q - degF)) : 0;
                int j = eidx[kk];
                float v = (DIN == 32) ? xin[j * 32 + f]
                                      : ((f < DIN) ? xin[j * DIN + f] : 0.f);
                float vF = (act && isF)  ? v : 0.f;
                float vB = (act && !isF) ? v : 0.f;
                switch (u & 3) {
                    case 0: rF0 += vF; rB0 += vB; break;
                    case 1: rF1 += vF; rB1 += vB; break;
                    case 2: rF2 += vF; rB2 += vB; break;
                    case 3: rF3 += vF; rB3 += vB; break;
                }
            }
        }
        float rawF = xr + ((rF0 + rF1) + (rF2 + rF3));
        float rawB = xr + ((rB0 + rB1) + (rB2 + rB3));

        float hinF = BN_IN ? fmaf(scale, rawF, (float)(degF + 1) * shift) : rawF;
        float hinB = BN_IN ? fmaf(scale, rawB, (float)(degB + 1) * shift) : rawB;

        float o = 0.f;
        #pragma unroll
        for (int dir = 0; dir < 2; dir++) {
            float hin = (dir == 0) ? hinF : hinB;

            float t1 = sb1[dir][f];
            #pragma unroll
            for (int i = 0; i < DIN; i++)
                t1 = fmaf(__shfl(hin, i, 32), sW1[dir][i * 32 + f], t1);
            t1 = fmaxf(t1, 0.f);

            float o2 = sb2[dir][f];
            #pragma unroll
            for (int i = 0; i < 32; i++)
                o2 = fmaf(__shfl(t1, i, 32), sW2[dir][i * 32 + f], o2);
            o += fmaxf(o2, 0.f);
        }
        o *= 0.5f;

        out[node * 32 + f] = o;
        bn_s  += o;
        bn_s2 += o * o;
    }

    atomicAdd(&sstat[f],      bn_s);
    atomicAdd(&sstat[32 + f], bn_s2);
    __syncthreads();
    if (tid < 64) atomicAdd(&stats[tid], sstat[tid]);
}

// ================= segmented mean-pool (batch is sorted) + head =============

__global__ void pool_seg(const float* __restrict__ h, const int* __restrict__ batch,
                         float* __restrict__ psum, float* __restrict__ pcnt, int n)
{
    int tid = threadIdx.x;
    int grp = tid >> 5, f = tid & 31;
    int base = blockIdx.x * 256;
    float acc = 0.f, cnt = 0.f;
    int curg = -1;
    for (int it = 0; it < 32; it++) {
        int nd = base + grp + it * 8;
        if (nd < n) {
            int g = batch[nd];
            if (g != curg) {
                if (curg >= 0) {
                    atomicAdd(&psum[curg * 32 + f], acc);
                    if (f == 0) atomicAdd(&pcnt[curg], cnt);
                }
                curg = g; acc = 0.f; cnt = 0.f;
            }
            acc += h[nd * 32 + f];
            cnt += 1.f;
        }
    }
    if (curg >= 0) {
        atomicAdd(&psum[curg * 32 + f], acc);
        if (f == 0) atomicAdd(&pcnt[curg], cnt);
    }
}

__global__ void head_kernel(const float* __restrict__ psum, const float* __restrict__ pcnt,
                            const float* __restrict__ stats3,
                            const float* __restrict__ g3, const float* __restrict__ b3,
                            const float* __restrict__ lbW, const float* __restrict__ lbb,
                            const float* __restrict__ lmW, const float* __restrict__ lmb,
                            float* __restrict__ out)
{
    int g = threadIdx.x;  // 512 threads, one block
    float cnt = fmaxf(pcnt[g], 1.0f);
    float inv = 1.0f / cnt;
    float p[32];
    #pragma unroll
    for (int i = 0; i < 32; i++) {
        float mu  = stats3[i] * INV_N;
        float var = stats3[32 + i] * INV_N - mu * mu;
        float a   = g3[i] * rsqrtf(var + BN_EPS);
        float b   = b3[i] - mu * a;
        p[i] = fmaf(a, psum[g * 32 + i] * inv, b);
    }
    float z = lmb[0];
    #pragma unroll
    for (int k = 0; k < 16; k++) {
        float acc = lbb[k];
        #pragma unroll
        for (int i = 0; i < 32; i++) acc += p[i] * lbW[i * 16 + k];
        z += fmaxf(acc, 0.0f) * lmW[k];
    }
    out[g] = 1.0f / (1.0f + expf(-z));
}

// ================= launcher =================================================

extern "C" void kernel_launch(void* const* d_in, const int* in_sizes, int n_in,
                              void* d_out, int out_size, void* d_ws, size_t ws_size,
                              hipStream_t stream)
{
    const float* x   = (const float*)d_in[0];
    const int* ei    = (const int*)d_in[1];
    const int* batch = (const int*)d_in[2];
    const int* src = ei;
    const int* dst = ei + N_EDGES;
    char* ws = (char*)d_ws;

    auto W = [&](int l, int j) { return (const float*)d_in[3 + (l - 1) * 10 + j]; };

    const size_t NEED_SPLIT = 118068368;  // split-path layout size

    if (ws_size >= NEED_SPLIT) {
        // ---------------- split path ----------------
        float* h    = (float*)(ws + 0);            // 32 MB
        float* agg  = (float*)(ws + 32000000);     // 64 MB (N x 64 fp32, interleaved F|B)
        int*   eidx = (int*)  (ws + 96000000);     // 20 MB
        int*   off  = (int*)  (ws + 116000000);    // (NT+1) ints
        // CSR-build temps live inside the agg region (dead after k_fill)
        int*   deg  = (int*)  (ws + 32000000);
        int*   cur  = (int*)  (ws + 34000016);
        int*   excl = (int*)  (ws + 36000016);
        int*   bsum = (int*)  (ws + 38000016);
        int*   boff = (int*)  (ws + 38004016);
        float* stats1 = (float*)(ws + 118000016);
        float* stats2 = stats1 + 64;
        float* stats3 = stats1 + 128;
        float* psum   = (float*)(ws + 118000784);
        float* pcnt   = (float*)(ws + 118066320);

        hipMemsetAsync(deg, 0, NT * 4, stream);
        hipMemsetAsync(cur, 0, NT * 4, stream);
        k_deg<<<(N_EDGES + 255) / 256, 256, 0, stream>>>(src, dst, deg, N_EDGES);
        int nb = (NT + 1023) / 1024;
        scan1<<<nb, 256, 0, stream>>>(deg, excl, bsum, NT);
        scan2<<<1, 512, 0, stream>>>(bsum, boff, nb);
        scan3<<<(NT + 256) / 256, 256, 0, stream>>>(excl, boff, off, NT);
        k_fill<<<(N_EDGES + 255) / 256, 256, 0, stream>>>(src, dst, off, cur, eidx, N_EDGES);

        hipMemsetAsync(stats1, 0, 3 * 64 * 4, stream);

        const int GG = 4096;
        const int NG = N_NODES / 8;   // 31250 node groups (both kernels)

        // layer 1 (DIN=6): x -> h, stats1
        gather_nbr<6><<<GG, 256, 0, stream>>>(x, off, eidx, agg, NG);
        dgin_mlp<6, false><<<GG, 256, 0, stream>>>(
            x, agg, off, nullptr, nullptr, nullptr,
            W(1,0), W(1,1), W(1,2), W(1,3), W(1,4), W(1,5), W(1,6), W(1,7),
            h, stats1, NG);

        // layer 2: h -> h (in place), stats2
        gather_nbr<32><<<GG, 256, 0, stream>>>(h, off, eidx, agg, NG);
        dgin_mlp<32, true><<<GG, 256, 0, stream>>>(
            h, agg, off, stats1, W(1,8), W(1,9),
            W(2,0), W(2,1), W(2,2), W(2,3), W(2,4), W(2,5), W(2,6), W(2,7),
            h, stats2, NG);

        // layer 3: h -> h (in place), stats3
        gather_nbr<32><<<GG, 256, 0, stream>>>(h, off, eidx, agg, NG);
        dgin_mlp<32, true><<<GG, 256, 0, stream>>>(
            h, agg, off, stats2, W(2,8), W(2,9),
            W(3,0), W(3,1), W(3,2), W(3,3), W(3,4), W(3,5), W(3,6), W(3,7),
            h, stats3, NG);

        hipMemsetAsync(psum, 0, (size_t)N_GRAPHS * 32 * 4, stream);
        hipMemsetAsync(pcnt, 0, (size_t)N_GRAPHS * 4, stream);
        pool_seg<<<(N_NODES + 255) / 256, 256, 0, stream>>>(h, batch, psum, pcnt, N_NODES);
        head_kernel<<<1, 512, 0, stream>>>(psum, pcnt, stats3, W(3,8), W(3,9),
            (const float*)d_in[33], (const float*)d_in[34],
            (const float*)d_in[35], (const float*)d_in[36],
            (float*)d_out);
    } else {
        // ---------------- fused fallback (R10) ----------------
        float* h_a    = (float*)(ws + 0);
        float* h_b    = (float*)(ws + 32000000);
        int*   eidx   = (int*)  (ws + 64000000);
        int*   off    = (int*)  (ws + 84000000);
        int*   deg    = (int*)  (ws + 86000016);
        int*   cur    = (int*)  (ws + 88000016);
        int*   excl   = (int*)  (ws + 90000016);
        int*   bsum   = (int*)  (ws + 92000016);
        int*   boff   = (int*)  (ws + 92004016);
        float* stats1 = (float*)(ws + 92008016);
        float* stats2 = (float*)(ws + 92008272);
        float* stats3 = (float*)(ws + 92008528);
        float* psum   = (float*)(ws + 92008784);
        float* pcnt   = (float*)(ws + 92074320);

        hipMemsetAsync(deg, 0, NT * 4, stream);
        hipMemsetAsync(cur, 0, NT * 4, stream);
        k_deg<<<(N_EDGES + 255) / 256, 256, 0, stream>>>(src, dst, deg, N_EDGES);
        int nb = (NT + 1023) / 1024;
        scan1<<<nb, 256, 0, stream>>>(deg, excl, bsum, NT);
        scan2<<<1, 512, 0, stream>>>(bsum, boff, nb);
        scan3<<<(NT + 256) / 256, 256, 0, stream>>>(excl, boff, off, NT);
        k_fill<<<(N_EDGES + 255) / 256, 256, 0, stream>>>(src, dst, off, cur, eidx, N_EDGES);

        const int NGROUPS = N_NODES / 8;
        const int GRID_G  = 4096;

        hipMemsetAsync(stats1, 0, 64 * 4, stream);
        hipMemsetAsync(stats2, 0, 64 * 4, stream);
        hipMemsetAsync(stats3, 0, 64 * 4, stream);

        dgin_gather<6, false><<<GRID_G, 256, 0, stream>>>(
            x, off, eidx, nullptr, nullptr, nullptr,
            W(1,0), W(1,1), W(1,2), W(1,3), W(1,4), W(1,5), W(1,6), W(1,7),
            h_a, stats1, NGROUPS);
        dgin_gather<32, true><<<GRID_G, 256, 0, stream>>>(
            h_a, off, eidx, stats1, W(1,8), W(1,9),
            W(2,0), W(2,1), W(2,2), W(2,3), W(2,4), W(2,5), W(2,6), W(2,7),
            h_b, stats2, NGROUPS);
        dgin_gather<32, true><<<GRID_G, 256, 0, stream>>>(
            h_b, off, eidx, stats2, W(2,8), W(2,9),
            W(3,0), W(3,1), W(3,2), W(3,3), W(3,4), W(3,5), W(3,6), W(3,7),
            h_a, stats3, NGROUPS);

        hipMemsetAsync(psum, 0, (size_t)N_GRAPHS * 32 * 4, stream);
        hipMemsetAsync(pcnt, 0, (size_t)N_GRAPHS * 4, stream);
        pool_seg<<<(N_NODES + 255) / 256, 256, 0, stream>>>(h_a, batch, psum, pcnt, N_NODES);
        head_kernel<<<1, 512, 0, stream>>>(psum, pcnt, stats3, W(3,8), W(3,9),
            (const float*)d_in[33], (const float*)d_in[34],
            (const float*)d_in[35], (const float*)d_in[36],
            (float*)d_out);
    }
}

// Round 14
// 1401.773 us; speedup vs baseline: 1.5245x; 1.5245x over previous
//
#include <hip/hip_runtime.h>
#include <math.h>

#define N_NODES 250000
#define N_EDGES 2500000
#define N_GRAPHS 512
#define BN_EPS 1e-5f
#define NT 500000   // 2*N_NODES degree/offset slots (F then B)
#define INV_N (1.0f / (float)N_NODES)

// ================= CSR build (per call; ws is re-poisoned every launch) =====

__global__ void k_deg(const int* __restrict__ src, const int* __restrict__ dst,
                      int* __restrict__ deg, int E)
{
    int e = blockIdx.x * blockDim.x + threadIdx.x;
    if (e >= E) return;
    atomicAdd(&deg[dst[e]], 1);            // F lists keyed by dst
    atomicAdd(&deg[N_NODES + src[e]], 1);  // B lists keyed by src
}

__global__ void scan1(const int* __restrict__ deg, int* __restrict__ excl,
                      int* __restrict__ bsum, int n)
{
    __shared__ int s[256];
    int t = threadIdx.x, b = blockIdx.x;
    int base = b * 1024 + t * 4;
    int v[4]; int tsum = 0;
    #pragma unroll
    for (int i = 0; i < 4; i++) { v[i] = (base + i < n) ? deg[base + i] : 0; tsum += v[i]; }
    s[t] = tsum; __syncthreads();
    for (int o = 1; o < 256; o <<= 1) {
        int x = (t >= o) ? s[t - o] : 0; __syncthreads();
        s[t] += x; __syncthreads();
    }
    int run = s[t] - tsum;
    #pragma unroll
    for (int i = 0; i < 4; i++) { if (base + i < n) excl[base + i] = run; run += v[i]; }
    if (t == 255) bsum[b] = s[255];
}

__global__ void scan2(const int* __restrict__ bsum, int* __restrict__ boff, int nb)
{
    __shared__ int s[512];
    int t = threadIdx.x;
    int v = (t < nb) ? bsum[t] : 0;
    s[t] = v; __syncthreads();
    for (int o = 1; o < 512; o <<= 1) {
        int x = (t >= o) ? s[t - o] : 0; __syncthreads();
        s[t] += x; __syncthreads();
    }
    if (t < nb) boff[t] = s[t] - v;
}

__global__ void scan3(const int* __restrict__ excl, const int* __restrict__ boff,
                      int* __restrict__ off, int n)
{
    int i = blockIdx.x * blockDim.x + threadIdx.x;
    if (i < n) off[i] = excl[i] + boff[i >> 10];
    if (i == 0) off[n] = 2 * N_EDGES;
}

__global__ void k_fill(const int* __restrict__ src, const int* __restrict__ dst,
                       const int* __restrict__ off, int* __restrict__ cur,
                       int* __restrict__ eidx, int E)
{
    int e = blockIdx.x * blockDim.x + threadIdx.x;
    if (e >= E) return;
    int s = src[e], d = dst[e];
    int pF = atomicAdd(&cur[d], 1);
    eidx[off[d] + pF] = s;
    int pB = atomicAdd(&cur[N_NODES + s], 1);
    eidx[off[N_NODES + s] + pB] = d;
}

// ================= SPLIT PATH ===============================================
// gather_nbr: pure neighbor-sum, both directions per node, interleaved record
// agg[node*2D + dir*D + f]. 8-wide predicated loop (R9-proven: FETCH near
// compulsory). (256,4): VGPR 64, proven config.

template <int DIN>
__global__ __launch_bounds__(256, 4)
void gather_nbr(const float* __restrict__ xin, const int* __restrict__ off,
                const int* __restrict__ eidx, float* __restrict__ agg, int ngroups)
{
    int tid = threadIdx.x;
    int f = tid & 31, hw = tid >> 5;
    for (int grp = blockIdx.x; grp < ngroups; grp += gridDim.x) {
        int node = grp * 8 + hw;
        #pragma unroll
        for (int dir = 0; dir < 2; dir++) {
            int u = dir * N_NODES + node;
            int k0 = off[u], k1 = off[u + 1];
            float r0 = 0.f, r1 = 0.f, r2 = 0.f, r3 = 0.f;
            for (int p = k0; p < k1; p += 8) {
                #pragma unroll
                for (int q = 0; q < 8; q++) {
                    int kk = p + q;
                    bool act = (kk < k1);
                    int j = eidx[act ? kk : k0];
                    float v;
                    if (DIN == 32) v = xin[j * 32 + f];
                    else           v = (f < DIN) ? xin[j * DIN + f] : 0.f;
                    v = act ? v : 0.f;
                    if ((q & 3) == 0)      r0 += v;
                    else if ((q & 3) == 1) r1 += v;
                    else if ((q & 3) == 2) r2 += v;
                    else                   r3 += v;
                }
            }
            float s = (r0 + r1) + (r2 + r3);
            if (DIN == 32)      agg[node * 64 + dir * 32 + f] = s;
            else if (f < DIN)   agg[node * (2 * DIN) + dir * DIN + f] = s;
        }
    }
}

// dgin_mlp2: THREAD-PER-NODE dual-direction GIN MLP + BN stats.
// R13 post-mortem: the lane-per-feature MLP was LDS-pipe-bound — 128
// ds_bpermute (__shfl) + 128 ds_read_b32 (weights) per NODE ≈ 300+ us of
// serialized LDS traffic per dispatch (invisible in VALUBusy). Thread-per-
// node reads each weight ONCE per 64 nodes (broadcast ds_read_b128, all
// lanes same address): 8x fewer LDS ops, zero shfls in the matmul.
// (256,1) -> 256-VGPR cap; ~170-reg live set fits, no spill (R2-proven).
// Input BN folded via LDS sscale/sshift (broadcast reads):
//   sum over (deg+1) rows of (a*v+b) = a*raw_sum + (deg+1)*b.

template <int DIN, bool BN_IN>
__global__ __launch_bounds__(256, 1)
void dgin_mlp2(const float* __restrict__ xin, const float* __restrict__ agg,
               const int* __restrict__ off,
               const float* __restrict__ in_stats,
               const float* __restrict__ in_g, const float* __restrict__ in_b,
               const float* __restrict__ W1f, const float* __restrict__ b1f,
               const float* __restrict__ W2f, const float* __restrict__ b2f,
               const float* __restrict__ W1b, const float* __restrict__ b1b,
               const float* __restrict__ W2b, const float* __restrict__ b2b,
               float* __restrict__ out, float* __restrict__ stats, int n)
{
    __shared__ __align__(16) float sW1[2][DIN * 32];
    __shared__ __align__(16) float sW2[2][32 * 32];
    __shared__ float sb1[2][32], sb2[2][32];
    __shared__ float sscale[32], sshift[32];
    __shared__ float sred[4 * 64];

    int tid = threadIdx.x;
    for (int i = tid; i < DIN * 32; i += 256) { sW1[0][i] = W1f[i]; sW1[1][i] = W1b[i]; }
    for (int i = tid; i < 32 * 32;  i += 256) { sW2[0][i] = W2f[i]; sW2[1][i] = W2b[i]; }
    if (tid < 32) {
        sb1[0][tid] = b1f[tid]; sb1[1][tid] = b1b[tid];
        sb2[0][tid] = b2f[tid]; sb2[1][tid] = b2b[tid];
        if (BN_IN) {
            float mu  = in_stats[tid] * INV_N;
            float var = in_stats[32 + tid] * INV_N - mu * mu;
            float sc  = in_g[tid] * rsqrtf(var + BN_EPS);
            sscale[tid] = sc;
            sshift[tid] = in_b[tid] - mu * sc;
        } else { sscale[tid] = 1.f; sshift[tid] = 0.f; }
    }
    __syncthreads();

    int n0 = blockIdx.x * 256 + tid;
    bool valid = (n0 < n);
    int node = valid ? n0 : (n - 1);

    // self row
    float xr[DIN];
    if (DIN == 32) {
        const float4* xp = (const float4*)(xin + node * 32);
        #pragma unroll
        for (int q = 0; q < 8; q++) {
            float4 w = xp[q];
            xr[4*q+0] = w.x; xr[4*q+1] = w.y; xr[4*q+2] = w.z; xr[4*q+3] = w.w;
        }
    } else {
        const float2* xp = (const float2*)(xin + node * DIN);
        #pragma unroll
        for (int q = 0; q < DIN / 2; q++) {
            float2 w = xp[q];
            xr[2*q+0] = w.x; xr[2*q+1] = w.y;
        }
    }

    float o[32];

    #pragma unroll
    for (int dir = 0; dir < 2; dir++) {
        // agg record for this node/dir (interleaved layout)
        float ag[DIN];
        if (DIN == 32) {
            const float4* ap = (const float4*)(agg + node * 64 + dir * 32);
            #pragma unroll
            for (int q = 0; q < 8; q++) {
                float4 w = ap[q];
                ag[4*q+0] = w.x; ag[4*q+1] = w.y; ag[4*q+2] = w.z; ag[4*q+3] = w.w;
            }
        } else {
            const float* ap = agg + node * (2 * DIN) + dir * DIN;
            #pragma unroll
            for (int i = 0; i < DIN; i++) ag[i] = ap[i];
        }
        int ob = dir * N_NODES + node;
        float degp1 = (float)(off[ob + 1] - off[ob] + 1);

        // layer 1: t1 = relu(b1 + hin @ W1), hin folded on the fly
        float t1[32];
        #pragma unroll
        for (int j = 0; j < 32; j++) t1[j] = sb1[dir][j];
        #pragma unroll
        for (int i = 0; i < DIN; i++) {
            float hv = xr[i] + ag[i];
            if (BN_IN) hv = fmaf(sscale[i], hv, degp1 * sshift[i]);
            const float4* wr = (const float4*)(&sW1[dir][i * 32]);
            #pragma unroll
            for (int q = 0; q < 8; q++) {
                float4 w = wr[q];
                t1[4*q+0] = fmaf(hv, w.x, t1[4*q+0]);
                t1[4*q+1] = fmaf(hv, w.y, t1[4*q+1]);
                t1[4*q+2] = fmaf(hv, w.z, t1[4*q+2]);
                t1[4*q+3] = fmaf(hv, w.w, t1[4*q+3]);
            }
        }
        #pragma unroll
        for (int j = 0; j < 32; j++) t1[j] = fmaxf(t1[j], 0.f);

        // layer 2
        float o2[32];
        #pragma unroll
        for (int j = 0; j < 32; j++) o2[j] = sb2[dir][j];
        #pragma unroll
        for (int i = 0; i < 32; i++) {
            float hv = t1[i];
            const float4* wr = (const float4*)(&sW2[dir][i * 32]);
            #pragma unroll
            for (int q = 0; q < 8; q++) {
                float4 w = wr[q];
                o2[4*q+0] = fmaf(hv, w.x, o2[4*q+0]);
                o2[4*q+1] = fmaf(hv, w.y, o2[4*q+1]);
                o2[4*q+2] = fmaf(hv, w.z, o2[4*q+2]);
                o2[4*q+3] = fmaf(hv, w.w, o2[4*q+3]);
            }
        }
        if (dir == 0) {
            #pragma unroll
            for (int j = 0; j < 32; j++) o[j] = fmaxf(o2[j], 0.f);
        } else {
            #pragma unroll
            for (int j = 0; j < 32; j++) o[j] = 0.5f * (o[j] + fmaxf(o2[j], 0.f));
        }
    }

    if (valid) {
        float4* op = (float4*)(out + node * 32);
        #pragma unroll
        for (int q = 0; q < 8; q++)
            op[q] = make_float4(o[4*q+0], o[4*q+1], o[4*q+2], o[4*q+3]);
    }

    // BN stats: wave shuffle reduce -> LDS cross-wave -> 64 atomics per block
    int lane = tid & 63;
    int wave = tid >> 6;
    #pragma unroll
    for (int f = 0; f < 32; f++) {
        float v = valid ? o[f] : 0.f;
        float v2 = v * v;
        #pragma unroll
        for (int offs = 32; offs > 0; offs >>= 1) {
            v  += __shfl_down(v, offs);
            v2 += __shfl_down(v2, offs);
        }
        if (lane == 0) {
            sred[wave * 64 + f]      = v;
            sred[wave * 64 + 32 + f] = v2;
        }
    }
    __syncthreads();
    if (tid < 64) {
        float a = sred[tid] + sred[64 + tid] + sred[128 + tid] + sred[192 + tid];
        atomicAdd(&stats[tid], a);
    }
}

// ================= FUSED PATH (R10 fallback, used if ws too small) ==========

template <int DIN, bool BN_IN>
__global__ __launch_bounds__(256, 2)
void dgin_gather(const float* __restrict__ xin,
                 const int* __restrict__ off, const int* __restrict__ eidx,
                 const float* __restrict__ in_stats,
                 const float* __restrict__ in_g, const float* __restrict__ in_b,
                 const float* __restrict__ W1f, const float* __restrict__ b1f,
                 const float* __restrict__ W2f, const float* __restrict__ b2f,
                 const float* __restrict__ W1b, const float* __restrict__ b1b,
                 const float* __restrict__ W2b, const float* __restrict__ b2b,
                 float* __restrict__ out, float* __restrict__ stats, int ngroups)
{
    __shared__ float sW1[2][DIN * 32];
    __shared__ float sW2[2][32 * 32];
    __shared__ float sb1[2][32], sb2[2][32];
    __shared__ float sstat[64];

    int tid = threadIdx.x;
    for (int i = tid; i < DIN * 32; i += 256) { sW1[0][i] = W1f[i]; sW1[1][i] = W1b[i]; }
    for (int i = tid; i < 32 * 32;  i += 256) { sW2[0][i] = W2f[i]; sW2[1][i] = W2b[i]; }
    if (tid < 32) { sb1[0][tid] = b1f[tid]; sb1[1][tid] = b1b[tid];
                    sb2[0][tid] = b2f[tid]; sb2[1][tid] = b2b[tid]; }
    if (tid < 64) sstat[tid] = 0.f;
    __syncthreads();

    int f  = tid & 31;
    int hw = tid >> 5;

    float scale = 1.f, shift = 0.f;
    if (BN_IN) {
        float mu  = in_stats[f] * INV_N;
        float var = in_stats[32 + f] * INV_N - mu * mu;
        scale = in_g[f] * rsqrtf(var + BN_EPS);
        shift = in_b[f] - mu * scale;
    }

    float bn_s = 0.f, bn_s2 = 0.f;

    for (int grp = blockIdx.x; grp < ngroups; grp += gridDim.x) {
        int node = grp * 8 + hw;

        float xr = (DIN == 32) ? xin[node * 32 + f]
                               : ((f < DIN) ? xin[node * DIN + f] : 0.f);

        int k0F = off[node],           k1F = off[node + 1];
        int k0B = off[N_NODES + node], k1B = off[N_NODES + node + 1];
        int degF = k1F - k0F, degB = k1B - k0B;
        int tot  = degF + degB;

        float rF0 = 0.f, rF1 = 0.f, rF2 = 0.f, rF3 = 0.f;
        float rB0 = 0.f, rB1 = 0.f, rB2 = 0.f, rB3 = 0.f;
        for (int p = 0; p < tot; p += 8) {
            #pragma unroll
            for (int u = 0; u < 8; u++) {
                int q = p + u;
                bool act = (q < tot);
                bool isF = (q < degF);
                int kk = act ? (isF ? (k0F + q) : (k0B + q - degF)) : 0;
                int j = eidx[kk];
                float v = (DIN == 32) ? xin[j * 32 + f]
                                      : ((f < DIN) ? xin[j * DIN + f] : 0.f);
                float vF = (act && isF)  ? v : 0.f;
                float vB = (act && !isF) ? v : 0.f;
                switch (u & 3) {
                    case 0: rF0 += vF; rB0 += vB; break;
                    case 1: rF1 += vF; rB1 += vB; break;
                    case 2: rF2 += vF; rB2 += vB; break;
                    case 3: rF3 += vF; rB3 += vB; break;
                }
            }
        }
        float rawF = xr + ((rF0 + rF1) + (rF2 + rF3));
        float rawB = xr + ((rB0 + rB1) + (rB2 + rB3));

        float hinF = BN_IN ? fmaf(scale, rawF, (float)(degF + 1) * shift) : rawF;
        float hinB = BN_IN ? fmaf(scale, rawB, (float)(degB + 1) * shift) : rawB;

        float o = 0.f;
        #pragma unroll
        for (int dir = 0; dir < 2; dir++) {
            float hin = (dir == 0) ? hinF : hinB;

            float t1 = sb1[dir][f];
            #pragma unroll
            for (int i = 0; i < DIN; i++)
                t1 = fmaf(__shfl(hin, i, 32), sW1[dir][i * 32 + f], t1);
            t1 = fmaxf(t1, 0.f);

            float o2 = sb2[dir][f];
            #pragma unroll
            for (int i = 0; i < 32; i++)
                o2 = fmaf(__shfl(t1, i, 32), sW2[dir][i * 32 + f], o2);
            o += fmaxf(o2, 0.f);
        }
        o *= 0.5f;

        out[node * 32 + f] = o;
        bn_s  += o;
        bn_s2 += o * o;
    }

    atomicAdd(&sstat[f],      bn_s);
    atomicAdd(&sstat[32 + f], bn_s2);
    __syncthreads();
    if (tid < 64) atomicAdd(&stats[tid], sstat[tid]);
}

// ================= segmented mean-pool (batch is sorted) + head =============

__global__ void pool_seg(const float* __restrict__ h, const int* __restrict__ batch,
                         float* __restrict__ psum, float* __restrict__ pcnt, int n)
{
    int tid = threadIdx.x;
    int grp = tid >> 5, f = tid & 31;
    int base = blockIdx.x * 256;
    float acc = 0.f, cnt = 0.f;
    int curg = -1;
    for (int it = 0; it < 32; it++) {
        int nd = base + grp + it * 8;
        if (nd < n) {
            int g = batch[nd];
            if (g != curg) {
                if (curg >= 0) {
                    atomicAdd(&psum[curg * 32 + f], acc);
                    if (f == 0) atomicAdd(&pcnt[curg], cnt);
                }
                curg = g; acc = 0.f; cnt = 0.f;
            }
            acc += h[nd * 32 + f];
            cnt += 1.f;
        }
    }
    if (curg >= 0) {
        atomicAdd(&psum[curg * 32 + f], acc);
        if (f == 0) atomicAdd(&pcnt[curg], cnt);
    }
}

__global__ void head_kernel(const float* __restrict__ psum, const float* __restrict__ pcnt,
                            const float* __restrict__ stats3,
                            const float* __restrict__ g3, const float* __restrict__ b3,
                            const float* __restrict__ lbW, const float* __restrict__ lbb,
                            const float* __restrict__ lmW, const float* __restrict__ lmb,
                            float* __restrict__ out)
{
    int g = threadIdx.x;  // 512 threads, one block
    float cnt = fmaxf(pcnt[g], 1.0f);
    float inv = 1.0f / cnt;
    float p[32];
    #pragma unroll
    for (int i = 0; i < 32; i++) {
        float mu  = stats3[i] * INV_N;
        float var = stats3[32 + i] * INV_N - mu * mu;
        float a   = g3[i] * rsqrtf(var + BN_EPS);
        float b   = b3[i] - mu * a;
        p[i] = fmaf(a, psum[g * 32 + i] * inv, b);
    }
    float z = lmb[0];
    #pragma unroll
    for (int k = 0; k < 16; k++) {
        float acc = lbb[k];
        #pragma unroll
        for (int i = 0; i < 32; i++) acc += p[i] * lbW[i * 16 + k];
        z += fmaxf(acc, 0.0f) * lmW[k];
    }
    out[g] = 1.0f / (1.0f + expf(-z));
}

// ================= launcher =================================================

extern "C" void kernel_launch(void* const* d_in, const int* in_sizes, int n_in,
                              void* d_out, int out_size, void* d_ws, size_t ws_size,
                              hipStream_t stream)
{
    const float* x   = (const float*)d_in[0];
    const int* ei    = (const int*)d_in[1];
    const int* batch = (const int*)d_in[2];
    const int* src = ei;
    const int* dst = ei + N_EDGES;
    char* ws = (char*)d_ws;

    auto W = [&](int l, int j) { return (const float*)d_in[3 + (l - 1) * 10 + j]; };

    const size_t NEED_SPLIT = 118068368;  // split-path layout size

    if (ws_size >= NEED_SPLIT) {
        // ---------------- split path ----------------
        float* h    = (float*)(ws + 0);            // 32 MB
        float* agg  = (float*)(ws + 32000000);     // 64 MB (N x 64 fp32, interleaved F|B)
        int*   eidx = (int*)  (ws + 96000000);     // 20 MB
        int*   off  = (int*)  (ws + 116000000);    // (NT+1) ints
        // CSR-build temps live inside the agg region (dead after k_fill)
        int*   deg  = (int*)  (ws + 32000000);
        int*   cur  = (int*)  (ws + 34000016);
        int*   excl = (int*)  (ws + 36000016);
        int*   bsum = (int*)  (ws + 38000016);
        int*   boff = (int*)  (ws + 38004016);
        float* stats1 = (float*)(ws + 118000016);
        float* stats2 = stats1 + 64;
        float* stats3 = stats1 + 128;
        float* psum   = (float*)(ws + 118000784);
        float* pcnt   = (float*)(ws + 118066320);

        hipMemsetAsync(deg, 0, NT * 4, stream);
        hipMemsetAsync(cur, 0, NT * 4, stream);
        k_deg<<<(N_EDGES + 255) / 256, 256, 0, stream>>>(src, dst, deg, N_EDGES);
        int nb = (NT + 1023) / 1024;
        scan1<<<nb, 256, 0, stream>>>(deg, excl, bsum, NT);
        scan2<<<1, 512, 0, stream>>>(bsum, boff, nb);
        scan3<<<(NT + 256) / 256, 256, 0, stream>>>(excl, boff, off, NT);
        k_fill<<<(N_EDGES + 255) / 256, 256, 0, stream>>>(src, dst, off, cur, eidx, N_EDGES);

        hipMemsetAsync(stats1, 0, 3 * 64 * 4, stream);

        const int GG = 4096;
        const int NG = N_NODES / 8;             // 31250 gather groups
        const int GM = (N_NODES + 255) / 256;   // 977 mlp blocks (thread-per-node)

        // layer 1 (DIN=6): x -> h, stats1
        gather_nbr<6><<<GG, 256, 0, stream>>>(x, off, eidx, agg, NG);
        dgin_mlp2<6, false><<<GM, 256, 0, stream>>>(
            x, agg, off, nullptr, nullptr, nullptr,
            W(1,0), W(1,1), W(1,2), W(1,3), W(1,4), W(1,5), W(1,6), W(1,7),
            h, stats1, N_NODES);

        // layer 2: h -> h (in place), stats2
        gather_nbr<32><<<GG, 256, 0, stream>>>(h, off, eidx, agg, NG);
        dgin_mlp2<32, true><<<GM, 256, 0, stream>>>(
            h, agg, off, stats1, W(1,8), W(1,9),
            W(2,0), W(2,1), W(2,2), W(2,3), W(2,4), W(2,5), W(2,6), W(2,7),
            h, stats2, N_NODES);

        // layer 3: h -> h (in place), stats3
        gather_nbr<32><<<GG, 256, 0, stream>>>(h, off, eidx, agg, NG);
        dgin_mlp2<32, true><<<GM, 256, 0, stream>>>(
            h, agg, off, stats2, W(2,8), W(2,9),
            W(3,0), W(3,1), W(3,2), W(3,3), W(3,4), W(3,5), W(3,6), W(3,7),
            h, stats3, N_NODES);

        hipMemsetAsync(psum, 0, (size_t)N_GRAPHS * 32 * 4, stream);
        hipMemsetAsync(pcnt, 0, (size_t)N_GRAPHS * 4, stream);
        pool_seg<<<(N_NODES + 255) / 256, 256, 0, stream>>>(h, batch, psum, pcnt, N_NODES);
        head_kernel<<<1, 512, 0, stream>>>(psum, pcnt, stats3, W(3,8), W(3,9),
            (const float*)d_in[33], (const float*)d_in[34],
            (const float*)d_in[35], (const float*)d_in[36],
            (float*)d_out);
    } else {
        // ---------------- fused fallback (R10) ----------------
        float* h_a    = (float*)(ws + 0);
        float* h_b    = (float*)(ws + 32000000);
        int*   eidx   = (int*)  (ws + 64000000);
        int*   off    = (int*)  (ws + 84000000);
        int*   deg    = (int*)  (ws + 86000016);
        int*   cur    = (int*)  (ws + 88000016);
        int*   excl   = (int*)  (ws + 90000016);
        int*   bsum   = (int*)  (ws + 92000016);
        int*   boff   = (int*)  (ws + 92004016);
        float* stats1 = (float*)(ws + 92008016);
        float* stats2 = (float*)(ws + 92008272);
        float* stats3 = (float*)(ws + 92008528);
        float* psum   = (float*)(ws + 92008784);
        float* pcnt   = (float*)(ws + 92074320);

        hipMemsetAsync(deg, 0, NT * 4, stream);
        hipMemsetAsync(cur, 0, NT * 4, stream);
        k_deg<<<(N_EDGES + 255) / 256, 256, 0, stream>>>(src, dst, deg, N_EDGES);
        int nb = (NT + 1023) / 1024;
        scan1<<<nb, 256, 0, stream>>>(deg, excl, bsum, NT);
        scan2<<<1, 512, 0, stream>>>(bsum, boff, nb);
        scan3<<<(NT + 256) / 256, 256, 0, stream>>>(excl, boff, off, NT);
        k_fill<<<(N_EDGES + 255) / 256, 256, 0, stream>>>(src, dst, off, cur, eidx, N_EDGES);

        const int NGROUPS = N_NODES / 8;
        const int GRID_G  = 4096;

        hipMemsetAsync(stats1, 0, 64 * 4, stream);
        hipMemsetAsync(stats2, 0, 64 * 4, stream);
        hipMemsetAsync(stats3, 0, 64 * 4, stream);

        dgin_gather<6, false><<<GRID_G, 256, 0, stream>>>(
            x, off, eidx, nullptr, nullptr, nullptr,
            W(1,0), W(1,1), W(1,2), W(1,3), W(1,4), W(1,5), W(1,6), W(1,7),
            h_a, stats1, NGROUPS);
        dgin_gather<32, true><<<GRID_G, 256, 0, stream>>>(
            h_a, off, eidx, stats1, W(1,8), W(1,9),
            W(2,0), W(2,1), W(2,2), W(2,3), W(2,4), W(2,5), W(2,6), W(2,7),
            h_b, stats2, NGROUPS);
        dgin_gather<32, true><<<GRID_G, 256, 0, stream>>>(
            h_b, off, eidx, stats2, W(2,8), W(2,9),
            W(3,0), W(3,1), W(3,2), W(3,3), W(3,4), W(3,5), W(3,6), W(3,7),
            h_a, stats3, NGROUPS);

        hipMemsetAsync(psum, 0, (size_t)N_GRAPHS * 32 * 4, stream);
        hipMemsetAsync(pcnt, 0, (size_t)N_GRAPHS * 4, stream);
        pool_seg<<<(N_NODES + 255) / 256, 256, 0, stream>>>(h_a, batch, psum, pcnt, N_NODES);
        head_kernel<<<1, 512, 0, stream>>>(psum, pcnt, stats3, W(3,8), W(3,9),
            (const float*)d_in[33], (const float*)d_in[34],
            (const float*)d_in[35], (const float*)d_in[36],
            (float*)d_out);
    }
}

// Round 15
// 1237.868 us; speedup vs baseline: 1.7264x; 1.1324x over previous
//
#include <hip/hip_runtime.h>
#include <math.h>

#define N_NODES 250000
#define N_EDGES 2500000
#define N_GRAPHS 512
#define BN_EPS 1e-5f
#define NT 500000   // 2*N_NODES degree/offset slots (F then B)
#define INV_N (1.0f / (float)N_NODES)

// ================= CSR build (per call; ws is re-poisoned every launch) =====
// k_rank: one pass computes degrees AND each edge's rank in its target list
// (the atomicAdd return value, previously discarded). k_fill2 then places
// edges with ZERO atomics: eidx[off[d] + rankF[e]] = src[e]. Halves the
// launch's atomic count 10M -> 5M; R14 showed k_fill at 20 G atomics/s was
// atomic-rate-bound (VALU 0.5%, occ 81%).

__global__ void k_rank(const int* __restrict__ src, const int* __restrict__ dst,
                       int* __restrict__ deg,
                       int* __restrict__ rankF, int* __restrict__ rankB, int E)
{
    int e = blockIdx.x * blockDim.x + threadIdx.x;
    if (e >= E) return;
    rankF[e] = atomicAdd(&deg[dst[e]], 1);            // F lists keyed by dst
    rankB[e] = atomicAdd(&deg[N_NODES + src[e]], 1);  // B lists keyed by src
}

__global__ void k_fill2(const int* __restrict__ src, const int* __restrict__ dst,
                        const int* __restrict__ off,
                        const int* __restrict__ rankF, const int* __restrict__ rankB,
                        int* __restrict__ eidx, int E)
{
    int e = blockIdx.x * blockDim.x + threadIdx.x;
    if (e >= E) return;
    int s = src[e], d = dst[e];
    eidx[off[d] + rankF[e]] = s;
    eidx[off[N_NODES + s] + rankB[e]] = d;
}

__global__ void scan1(const int* __restrict__ deg, int* __restrict__ excl,
                      int* __restrict__ bsum, int n)
{
    __shared__ int s[256];
    int t = threadIdx.x, b = blockIdx.x;
    int base = b * 1024 + t * 4;
    int v[4]; int tsum = 0;
    #pragma unroll
    for (int i = 0; i < 4; i++) { v[i] = (base + i < n) ? deg[base + i] : 0; tsum += v[i]; }
    s[t] = tsum; __syncthreads();
    for (int o = 1; o < 256; o <<= 1) {
        int x = (t >= o) ? s[t - o] : 0; __syncthreads();
        s[t] += x; __syncthreads();
    }
    int run = s[t] - tsum;
    #pragma unroll
    for (int i = 0; i < 4; i++) { if (base + i < n) excl[base + i] = run; run += v[i]; }
    if (t == 255) bsum[b] = s[255];
}

__global__ void scan2(const int* __restrict__ bsum, int* __restrict__ boff, int nb)
{
    __shared__ int s[512];
    int t = threadIdx.x;
    int v = (t < nb) ? bsum[t] : 0;
    s[t] = v; __syncthreads();
    for (int o = 1; o < 512; o <<= 1) {
        int x = (t >= o) ? s[t - o] : 0; __syncthreads();
        s[t] += x; __syncthreads();
    }
    if (t < nb) boff[t] = s[t] - v;
}

__global__ void scan3(const int* __restrict__ excl, const int* __restrict__ boff,
                      int* __restrict__ off, int n)
{
    int i = blockIdx.x * blockDim.x + threadIdx.x;
    if (i < n) off[i] = excl[i] + boff[i >> 10];
    if (i == 0) off[n] = 2 * N_EDGES;
}

// ================= SPLIT PATH ===============================================
// gather_nbr: pure neighbor-sum, both directions per node, interleaved record
// agg[node*2D + dir*D + f]. 8-wide predicated loop (R9-proven).

template <int DIN>
__global__ __launch_bounds__(256, 4)
void gather_nbr(const float* __restrict__ xin, const int* __restrict__ off,
                const int* __restrict__ eidx, float* __restrict__ agg, int ngroups)
{
    int tid = threadIdx.x;
    int f = tid & 31, hw = tid >> 5;
    for (int grp = blockIdx.x; grp < ngroups; grp += gridDim.x) {
        int node = grp * 8 + hw;
        #pragma unroll
        for (int dir = 0; dir < 2; dir++) {
            int u = dir * N_NODES + node;
            int k0 = off[u], k1 = off[u + 1];
            float r0 = 0.f, r1 = 0.f, r2 = 0.f, r3 = 0.f;
            for (int p = k0; p < k1; p += 8) {
                #pragma unroll
                for (int q = 0; q < 8; q++) {
                    int kk = p + q;
                    bool act = (kk < k1);
                    int j = eidx[act ? kk : k0];
                    float v;
                    if (DIN == 32) v = xin[j * 32 + f];
                    else           v = (f < DIN) ? xin[j * DIN + f] : 0.f;
                    v = act ? v : 0.f;
                    if ((q & 3) == 0)      r0 += v;
                    else if ((q & 3) == 1) r1 += v;
                    else if ((q & 3) == 2) r2 += v;
                    else                   r3 += v;
                }
            }
            float s = (r0 + r1) + (r2 + r3);
            if (DIN == 32)      agg[node * 64 + dir * 32 + f] = s;
            else if (f < DIN)   agg[node * (2 * DIN) + dir * DIN + f] = s;
        }
    }
}

// dgin_mlp2: THREAD-PER-NODE dual-direction GIN MLP + BN stats (R14 win:
// broadcast ds_read_b128 weights, zero shfls in the matmul — the
// lane-per-feature version was LDS-pipe-bound at ~500us/dispatch).
// (256,1) -> 256-VGPR cap; ~170-reg live set fits, no spill.
// Input BN folded: sum over (deg+1) rows of (a*v+b) = a*raw_sum + (deg+1)*b.

template <int DIN, bool BN_IN>
__global__ __launch_bounds__(256, 1)
void dgin_mlp2(const float* __restrict__ xin, const float* __restrict__ agg,
               const int* __restrict__ off,
               const float* __restrict__ in_stats,
               const float* __restrict__ in_g, const float* __restrict__ in_b,
               const float* __restrict__ W1f, const float* __restrict__ b1f,
               const float* __restrict__ W2f, const float* __restrict__ b2f,
               const float* __restrict__ W1b, const float* __restrict__ b1b,
               const float* __restrict__ W2b, const float* __restrict__ b2b,
               float* __restrict__ out, float* __restrict__ stats, int n)
{
    __shared__ __align__(16) float sW1[2][DIN * 32];
    __shared__ __align__(16) float sW2[2][32 * 32];
    __shared__ float sb1[2][32], sb2[2][32];
    __shared__ float sscale[32], sshift[32];
    __shared__ float sred[4 * 64];

    int tid = threadIdx.x;
    for (int i = tid; i < DIN * 32; i += 256) { sW1[0][i] = W1f[i]; sW1[1][i] = W1b[i]; }
    for (int i = tid; i < 32 * 32;  i += 256) { sW2[0][i] = W2f[i]; sW2[1][i] = W2b[i]; }
    if (tid < 32) {
        sb1[0][tid] = b1f[tid]; sb1[1][tid] = b1b[tid];
        sb2[0][tid] = b2f[tid]; sb2[1][tid] = b2b[tid];
        if (BN_IN) {
            float mu  = in_stats[tid] * INV_N;
            float var = in_stats[32 + tid] * INV_N - mu * mu;
            float sc  = in_g[tid] * rsqrtf(var + BN_EPS);
            sscale[tid] = sc;
            sshift[tid] = in_b[tid] - mu * sc;
        } else { sscale[tid] = 1.f; sshift[tid] = 0.f; }
    }
    __syncthreads();

    int n0 = blockIdx.x * 256 + tid;
    bool valid = (n0 < n);
    int node = valid ? n0 : (n - 1);

    float xr[DIN];
    if (DIN == 32) {
        const float4* xp = (const float4*)(xin + node * 32);
        #pragma unroll
        for (int q = 0; q < 8; q++) {
            float4 w = xp[q];
            xr[4*q+0] = w.x; xr[4*q+1] = w.y; xr[4*q+2] = w.z; xr[4*q+3] = w.w;
        }
    } else {
        const float2* xp = (const float2*)(xin + node * DIN);
        #pragma unroll
        for (int q = 0; q < DIN / 2; q++) {
            float2 w = xp[q];
            xr[2*q+0] = w.x; xr[2*q+1] = w.y;
        }
    }

    float o[32];

    #pragma unroll
    for (int dir = 0; dir < 2; dir++) {
        float ag[DIN];
        if (DIN == 32) {
            const float4* ap = (const float4*)(agg + node * 64 + dir * 32);
            #pragma unroll
            for (int q = 0; q < 8; q++) {
                float4 w = ap[q];
                ag[4*q+0] = w.x; ag[4*q+1] = w.y; ag[4*q+2] = w.z; ag[4*q+3] = w.w;
            }
        } else {
            const float* ap = agg + node * (2 * DIN) + dir * DIN;
            #pragma unroll
            for (int i = 0; i < DIN; i++) ag[i] = ap[i];
        }
        int ob = dir * N_NODES + node;
        float degp1 = (float)(off[ob + 1] - off[ob] + 1);

        float t1[32];
        #pragma unroll
        for (int j = 0; j < 32; j++) t1[j] = sb1[dir][j];
        #pragma unroll
        for (int i = 0; i < DIN; i++) {
            float hv = xr[i] + ag[i];
            if (BN_IN) hv = fmaf(sscale[i], hv, degp1 * sshift[i]);
            const float4* wr = (const float4*)(&sW1[dir][i * 32]);
            #pragma unroll
            for (int q = 0; q < 8; q++) {
                float4 w = wr[q];
                t1[4*q+0] = fmaf(hv, w.x, t1[4*q+0]);
                t1[4*q+1] = fmaf(hv, w.y, t1[4*q+1]);
                t1[4*q+2] = fmaf(hv, w.z, t1[4*q+2]);
                t1[4*q+3] = fmaf(hv, w.w, t1[4*q+3]);
            }
        }
        #pragma unroll
        for (int j = 0; j < 32; j++) t1[j] = fmaxf(t1[j], 0.f);

        float o2[32];
        #pragma unroll
        for (int j = 0; j < 32; j++) o2[j] = sb2[dir][j];
        #pragma unroll
        for (int i = 0; i < 32; i++) {
            float hv = t1[i];
            const float4* wr = (const float4*)(&sW2[dir][i * 32]);
            #pragma unroll
            for (int q = 0; q < 8; q++) {
                float4 w = wr[q];
                o2[4*q+0] = fmaf(hv, w.x, o2[4*q+0]);
                o2[4*q+1] = fmaf(hv, w.y, o2[4*q+1]);
                o2[4*q+2] = fmaf(hv, w.z, o2[4*q+2]);
                o2[4*q+3] = fmaf(hv, w.w, o2[4*q+3]);
            }
        }
        if (dir == 0) {
            #pragma unroll
            for (int j = 0; j < 32; j++) o[j] = fmaxf(o2[j], 0.f);
        } else {
            #pragma unroll
            for (int j = 0; j < 32; j++) o[j] = 0.5f * (o[j] + fmaxf(o2[j], 0.f));
        }
    }

    if (valid) {
        float4* op = (float4*)(out + node * 32);
        #pragma unroll
        for (int q = 0; q < 8; q++)
            op[q] = make_float4(o[4*q+0], o[4*q+1], o[4*q+2], o[4*q+3]);
    }

    int lane = tid & 63;
    int wave = tid >> 6;
    #pragma unroll
    for (int f = 0; f < 32; f++) {
        float v = valid ? o[f] : 0.f;
        float v2 = v * v;
        #pragma unroll
        for (int offs = 32; offs > 0; offs >>= 1) {
            v  += __shfl_down(v, offs);
            v2 += __shfl_down(v2, offs);
        }
        if (lane == 0) {
            sred[wave * 64 + f]      = v;
            sred[wave * 64 + 32 + f] = v2;
        }
    }
    __syncthreads();
    if (tid < 64) {
        float a = sred[tid] + sred[64 + tid] + sred[128 + tid] + sred[192 + tid];
        atomicAdd(&stats[tid], a);
    }
}

// ================= segmented mean-pool (batch is sorted) + head =============

__global__ void pool_seg(const float* __restrict__ h, const int* __restrict__ batch,
                         float* __restrict__ psum, float* __restrict__ pcnt, int n)
{
    int tid = threadIdx.x;
    int grp = tid >> 5, f = tid & 31;
    int base = blockIdx.x * 256;
    float acc = 0.f, cnt = 0.f;
    int curg = -1;
    for (int it = 0; it < 32; it++) {
        int nd = base + grp + it * 8;
        if (nd < n) {
            int g = batch[nd];
            if (g != curg) {
                if (curg >= 0) {
                    atomicAdd(&psum[curg * 32 + f], acc);
                    if (f == 0) atomicAdd(&pcnt[curg], cnt);
                }
                curg = g; acc = 0.f; cnt = 0.f;
            }
            acc += h[nd * 32 + f];
            cnt += 1.f;
        }
    }
    if (curg >= 0) {
        atomicAdd(&psum[curg * 32 + f], acc);
        if (f == 0) atomicAdd(&pcnt[curg], cnt);
    }
}

__global__ void head_kernel(const float* __restrict__ psum, const float* __restrict__ pcnt,
                            const float* __restrict__ stats3,
                            const float* __restrict__ g3, const float* __restrict__ b3,
                            const float* __restrict__ lbW, const float* __restrict__ lbb,
                            const float* __restrict__ lmW, const float* __restrict__ lmb,
                            float* __restrict__ out)
{
    int g = threadIdx.x;  // 512 threads, one block
    float cnt = fmaxf(pcnt[g], 1.0f);
    float inv = 1.0f / cnt;
    float p[32];
    #pragma unroll
    for (int i = 0; i < 32; i++) {
        float mu  = stats3[i] * INV_N;
        float var = stats3[32 + i] * INV_N - mu * mu;
        float a   = g3[i] * rsqrtf(var + BN_EPS);
        float b   = b3[i] - mu * a;
        p[i] = fmaf(a, psum[g * 32 + i] * inv, b);
    }
    float z = lmb[0];
    #pragma unroll
    for (int k = 0; k < 16; k++) {
        float acc = lbb[k];
        #pragma unroll
        for (int i = 0; i < 32; i++) acc += p[i] * lbW[i * 16 + k];
        z += fmaxf(acc, 0.0f) * lmW[k];
    }
    out[g] = 1.0f / (1.0f + expf(-z));
}

// ================= launcher =================================================

extern "C" void kernel_launch(void* const* d_in, const int* in_sizes, int n_in,
                              void* d_out, int out_size, void* d_ws, size_t ws_size,
                              hipStream_t stream)
{
    const float* x   = (const float*)d_in[0];
    const int* ei    = (const int*)d_in[1];
    const int* batch = (const int*)d_in[2];
    const int* src = ei;
    const int* dst = ei + N_EDGES;
    char* ws = (char*)d_ws;

    auto W = [&](int l, int j) { return (const float*)d_in[3 + (l - 1) * 10 + j]; };

    // ---------------- split path layout ----------------
    float* h    = (float*)(ws + 0);            // 32 MB
    float* agg  = (float*)(ws + 32000000);     // 64 MB (N x 64 fp32, interleaved F|B)
    int*   eidx = (int*)  (ws + 96000000);     // 20 MB
    int*   off  = (int*)  (ws + 116000000);    // (NT+1) ints
    // CSR-build temps live inside the agg region (dead until first gather)
    int*   deg   = (int*)  (ws + 32000000);    // 2 MB
    int*   excl  = (int*)  (ws + 34000016);    // 2 MB
    int*   bsum  = (int*)  (ws + 36000016);    // ~2 KB
    int*   boff  = (int*)  (ws + 36004016);    // ~2 KB
    int*   rankF = (int*)  (ws + 38000016);    // 10 MB
    int*   rankB = (int*)  (ws + 48000016);    // 10 MB  (ends 58 MB < 96 MB)
    float* stats1 = (float*)(ws + 118000016);
    float* stats2 = stats1 + 64;
    float* stats3 = stats1 + 128;
    float* psum   = (float*)(ws + 118000784);
    float* pcnt   = (float*)(ws + 118066320);

    // ---- CSR build: rank pass (atomics) -> scan -> atomic-free fill
    hipMemsetAsync(deg, 0, NT * 4, stream);
    k_rank<<<(N_EDGES + 255) / 256, 256, 0, stream>>>(src, dst, deg, rankF, rankB, N_EDGES);
    int nb = (NT + 1023) / 1024;
    scan1<<<nb, 256, 0, stream>>>(deg, excl, bsum, NT);
    scan2<<<1, 512, 0, stream>>>(bsum, boff, nb);
    scan3<<<(NT + 256) / 256, 256, 0, stream>>>(excl, boff, off, NT);
    k_fill2<<<(N_EDGES + 255) / 256, 256, 0, stream>>>(src, dst, off, rankF, rankB, eidx, N_EDGES);

    hipMemsetAsync(stats1, 0, 3 * 64 * 4, stream);

    const int GG = 4096;
    const int NG = N_NODES / 8;             // 31250 gather groups
    const int GM = (N_NODES + 255) / 256;   // 977 mlp blocks (thread-per-node)

    // layer 1 (DIN=6): x -> h, stats1
    gather_nbr<6><<<GG, 256, 0, stream>>>(x, off, eidx, agg, NG);
    dgin_mlp2<6, false><<<GM, 256, 0, stream>>>(
        x, agg, off, nullptr, nullptr, nullptr,
        W(1,0), W(1,1), W(1,2), W(1,3), W(1,4), W(1,5), W(1,6), W(1,7),
        h, stats1, N_NODES);

    // layer 2: h -> h (in place), stats2
    gather_nbr<32><<<GG, 256, 0, stream>>>(h, off, eidx, agg, NG);
    dgin_mlp2<32, true><<<GM, 256, 0, stream>>>(
        h, agg, off, stats1, W(1,8), W(1,9),
        W(2,0), W(2,1), W(2,2), W(2,3), W(2,4), W(2,5), W(2,6), W(2,7),
        h, stats2, N_NODES);

    // layer 3: h -> h (in place), stats3
    gather_nbr<32><<<GG, 256, 0, stream>>>(h, off, eidx, agg, NG);
    dgin_mlp2<32, true><<<GM, 256, 0, stream>>>(
        h, agg, off, stats2, W(2,8), W(2,9),
        W(3,0), W(3,1), W(3,2), W(3,3), W(3,4), W(3,5), W(3,6), W(3,7),
        h, stats3, N_NODES);

    hipMemsetAsync(psum, 0, (size_t)N_GRAPHS * 32 * 4, stream);
    hipMemsetAsync(pcnt, 0, (size_t)N_GRAPHS * 4, stream);
    pool_seg<<<(N_NODES + 255) / 256, 256, 0, stream>>>(h, batch, psum, pcnt, N_NODES);
    head_kernel<<<1, 512, 0, stream>>>(psum, pcnt, stats3, W(3,8), W(3,9),
        (const float*)d_in[33], (const float*)d_in[34],
        (const float*)d_in[35], (const float*)d_in[36],
        (float*)d_out);
}

// Round 16
// 1197.446 us; speedup vs baseline: 1.7847x; 1.0338x over previous
//
#include <hip/hip_runtime.h>
#include <math.h>

#define N_NODES 250000
#define N_EDGES 2500000
#define N_GRAPHS 512
#define BN_EPS 1e-5f
#define NT 500000   // 2*N_NODES degree/offset slots (F then B)
#define INV_N (1.0f / (float)N_NODES)

// bf16 helpers (RNE); bf16->fp32 is an exact bit shift.
__device__ __forceinline__ unsigned short f2bf(float x) {
    unsigned int u = __float_as_uint(x);
    unsigned int r = (u + 0x7FFFu + ((u >> 16) & 1u)) >> 16;
    return (unsigned short)r;
}
__device__ __forceinline__ float bf2f(unsigned short b) {
    return __uint_as_float(((unsigned int)b) << 16);
}

// ================= CSR build (per call; ws is re-poisoned every launch) =====
// k_rank: computes degrees AND each edge's rank (atomicAdd return value),
// packed rankF|rankB<<16 into ONE u32/edge. k_fill2 places edges with ZERO
// atomics (R15 win). Max degree << 65536 for E/N = 10 random edges.

__global__ void k_rank(const int* __restrict__ src, const int* __restrict__ dst,
                       int* __restrict__ deg, int* __restrict__ rank, int E)
{
    int e = blockIdx.x * blockDim.x + threadIdx.x;
    if (e >= E) return;
    int rF = atomicAdd(&deg[dst[e]], 1);            // F lists keyed by dst
    int rB = atomicAdd(&deg[N_NODES + src[e]], 1);  // B lists keyed by src
    rank[e] = rF | (rB << 16);
}

__global__ void k_fill2(const int* __restrict__ src, const int* __restrict__ dst,
                        const int* __restrict__ off, const int* __restrict__ rank,
                        int* __restrict__ eidx, int E)
{
    int e = blockIdx.x * blockDim.x + threadIdx.x;
    if (e >= E) return;
    int s = src[e], d = dst[e];
    int r = rank[e];
    eidx[off[d] + (r & 0xFFFF)] = s;
    eidx[off[N_NODES + s] + (r >> 16)] = d;
}

__global__ void scan1(const int* __restrict__ deg, int* __restrict__ excl,
                      int* __restrict__ bsum, int n)
{
    __shared__ int s[256];
    int t = threadIdx.x, b = blockIdx.x;
    int base = b * 1024 + t * 4;
    int v[4]; int tsum = 0;
    #pragma unroll
    for (int i = 0; i < 4; i++) { v[i] = (base + i < n) ? deg[base + i] : 0; tsum += v[i]; }
    s[t] = tsum; __syncthreads();
    for (int o = 1; o < 256; o <<= 1) {
        int x = (t >= o) ? s[t - o] : 0; __syncthreads();
        s[t] += x; __syncthreads();
    }
    int run = s[t] - tsum;
    #pragma unroll
    for (int i = 0; i < 4; i++) { if (base + i < n) excl[base + i] = run; run += v[i]; }
    if (t == 255) bsum[b] = s[255];
}

__global__ void scan2(const int* __restrict__ bsum, int* __restrict__ boff, int nb)
{
    __shared__ int s[512];
    int t = threadIdx.x;
    int v = (t < nb) ? bsum[t] : 0;
    s[t] = v; __syncthreads();
    for (int o = 1; o < 512; o <<= 1) {
        int x = (t >= o) ? s[t - o] : 0; __syncthreads();
        s[t] += x; __syncthreads();
    }
    if (t < nb) boff[t] = s[t] - v;
}

__global__ void scan3(const int* __restrict__ excl, const int* __restrict__ boff,
                      int* __restrict__ off, int n)
{
    int i = blockIdx.x * blockDim.x + threadIdx.x;
    if (i < n) off[i] = excl[i] + boff[i >> 10];
    if (i == 0) off[n] = 2 * N_EDGES;
}

// ================= gather: pure neighbor-sum, both dirs, 8-wide =============
// h is stored bf16 (64B rows): R8's "bytes don't matter" conclusion was
// regime-specific (fused kernel was latency-bound). The pure gather is
// BW-bound on L3 random-row service (16 waves/CU x 16 rows in flight);
// a bf16 row is exactly one 64B granule -> halves L3-side traffic.
// bf16->fp32 read is a free bit shift. agg stays fp32 (streamed once).

template <int DIN, bool IN_BF16>
__global__ __launch_bounds__(256, 4)
void gather_nbr(const void* __restrict__ xin_v, const int* __restrict__ off,
                const int* __restrict__ eidx, float* __restrict__ agg, int ngroups)
{
    const float* xf = (const float*)xin_v;
    const unsigned short* xb = (const unsigned short*)xin_v;
    int tid = threadIdx.x;
    int f = tid & 31, hw = tid >> 5;
    for (int grp = blockIdx.x; grp < ngroups; grp += gridDim.x) {
        int node = grp * 8 + hw;
        #pragma unroll
        for (int dir = 0; dir < 2; dir++) {
            int u = dir * N_NODES + node;
            int k0 = off[u], k1 = off[u + 1];
            float r0 = 0.f, r1 = 0.f, r2 = 0.f, r3 = 0.f;
            for (int p = k0; p < k1; p += 8) {
                #pragma unroll
                for (int q = 0; q < 8; q++) {
                    int kk = p + q;
                    bool act = (kk < k1);
                    int j = eidx[act ? kk : k0];
                    float v;
                    if (IN_BF16)        v = bf2f(xb[j * 32 + f]);
                    else if (DIN == 32) v = xf[j * 32 + f];
                    else                v = (f < DIN) ? xf[j * DIN + f] : 0.f;
                    v = act ? v : 0.f;
                    if ((q & 3) == 0)      r0 += v;
                    else if ((q & 3) == 1) r1 += v;
                    else if ((q & 3) == 2) r2 += v;
                    else                   r3 += v;
                }
            }
            float s = (r0 + r1) + (r2 + r3);
            if (DIN == 32)      agg[node * 64 + dir * 32 + f] = s;
            else if (f < DIN)   agg[node * (2 * DIN) + dir * DIN + f] = s;
        }
    }
}

// ================= thread-per-node dual-direction GIN MLP + BN stats ========
// R14 win: broadcast ds_read_b128 weights, zero shfls (lane-per-feature MLP
// was LDS-pipe-bound). (256,1) -> 256-VGPR cap, no spill. Output h in bf16;
// BN stats accumulate the ROUNDED values so next layer's folded BN is
// self-consistent with stored data:
//   sum over (deg+1) rows of (a*v+b) = a*raw_sum + (deg+1)*b.

template <int DIN, bool BN_IN, bool IN_BF16>
__global__ __launch_bounds__(256, 1)
void dgin_mlp2(const void* __restrict__ xin_v, const float* __restrict__ agg,
               const int* __restrict__ off,
               const float* __restrict__ in_stats,
               const float* __restrict__ in_g, const float* __restrict__ in_b,
               const float* __restrict__ W1f, const float* __restrict__ b1f,
               const float* __restrict__ W2f, const float* __restrict__ b2f,
               const float* __restrict__ W1b, const float* __restrict__ b1b,
               const float* __restrict__ W2b, const float* __restrict__ b2b,
               unsigned short* __restrict__ out, float* __restrict__ stats, int n)
{
    const float* xf = (const float*)xin_v;
    const unsigned short* xb = (const unsigned short*)xin_v;

    __shared__ __align__(16) float sW1[2][DIN * 32];
    __shared__ __align__(16) float sW2[2][32 * 32];
    __shared__ float sb1[2][32], sb2[2][32];
    __shared__ float sscale[32], sshift[32];
    __shared__ float sred[4 * 64];

    int tid = threadIdx.x;
    for (int i = tid; i < DIN * 32; i += 256) { sW1[0][i] = W1f[i]; sW1[1][i] = W1b[i]; }
    for (int i = tid; i < 32 * 32;  i += 256) { sW2[0][i] = W2f[i]; sW2[1][i] = W2b[i]; }
    if (tid < 32) {
        sb1[0][tid] = b1f[tid]; sb1[1][tid] = b1b[tid];
        sb2[0][tid] = b2f[tid]; sb2[1][tid] = b2b[tid];
        if (BN_IN) {
            float mu  = in_stats[tid] * INV_N;
            float var = in_stats[32 + tid] * INV_N - mu * mu;
            float sc  = in_g[tid] * rsqrtf(var + BN_EPS);
            sscale[tid] = sc;
            sshift[tid] = in_b[tid] - mu * sc;
        } else { sscale[tid] = 1.f; sshift[tid] = 0.f; }
    }
    __syncthreads();

    int n0 = blockIdx.x * 256 + tid;
    bool valid = (n0 < n);
    int node = valid ? n0 : (n - 1);

    // self row
    float xr[DIN];
    if (IN_BF16) {
        const uint4* xp = (const uint4*)(xb + node * 32);
        #pragma unroll
        for (int q = 0; q < 4; q++) {
            uint4 u = xp[q];
            unsigned int w[4] = {u.x, u.y, u.z, u.w};
            #pragma unroll
            for (int k = 0; k < 4; k++) {
                xr[8*q + 2*k]     = __uint_as_float(w[k] << 16);
                xr[8*q + 2*k + 1] = __uint_as_float(w[k] & 0xFFFF0000u);
            }
        }
    } else if (DIN == 32) {
        const float4* xp = (const float4*)(xf + node * 32);
        #pragma unroll
        for (int q = 0; q < 8; q++) {
            float4 w = xp[q];
            xr[4*q+0] = w.x; xr[4*q+1] = w.y; xr[4*q+2] = w.z; xr[4*q+3] = w.w;
        }
    } else {
        const float2* xp = (const float2*)(xf + node * DIN);
        #pragma unroll
        for (int q = 0; q < DIN / 2; q++) {
            float2 w = xp[q];
            xr[2*q+0] = w.x; xr[2*q+1] = w.y;
        }
    }

    float o[32];

    #pragma unroll
    for (int dir = 0; dir < 2; dir++) {
        float ag[DIN];
        if (DIN == 32) {
            const float4* ap = (const float4*)(agg + node * 64 + dir * 32);
            #pragma unroll
            for (int q = 0; q < 8; q++) {
                float4 w = ap[q];
                ag[4*q+0] = w.x; ag[4*q+1] = w.y; ag[4*q+2] = w.z; ag[4*q+3] = w.w;
            }
        } else {
            const float* ap = agg + node * (2 * DIN) + dir * DIN;
            #pragma unroll
            for (int i = 0; i < DIN; i++) ag[i] = ap[i];
        }
        int ob = dir * N_NODES + node;
        float degp1 = (float)(off[ob + 1] - off[ob] + 1);

        float t1[32];
        #pragma unroll
        for (int j = 0; j < 32; j++) t1[j] = sb1[dir][j];
        #pragma unroll
        for (int i = 0; i < DIN; i++) {
            float hv = xr[i] + ag[i];
            if (BN_IN) hv = fmaf(sscale[i], hv, degp1 * sshift[i]);
            const float4* wr = (const float4*)(&sW1[dir][i * 32]);
            #pragma unroll
            for (int q = 0; q < 8; q++) {
                float4 w = wr[q];
                t1[4*q+0] = fmaf(hv, w.x, t1[4*q+0]);
                t1[4*q+1] = fmaf(hv, w.y, t1[4*q+1]);
                t1[4*q+2] = fmaf(hv, w.z, t1[4*q+2]);
                t1[4*q+3] = fmaf(hv, w.w, t1[4*q+3]);
            }
        }
        #pragma unroll
        for (int j = 0; j < 32; j++) t1[j] = fmaxf(t1[j], 0.f);

        float o2[32];
        #pragma unroll
        for (int j = 0; j < 32; j++) o2[j] = sb2[dir][j];
        #pragma unroll
        for (int i = 0; i < 32; i++) {
            float hv = t1[i];
            const float4* wr = (const float4*)(&sW2[dir][i * 32]);
            #pragma unroll
            for (int q = 0; q < 8; q++) {
                float4 w = wr[q];
                o2[4*q+0] = fmaf(hv, w.x, o2[4*q+0]);
                o2[4*q+1] = fmaf(hv, w.y, o2[4*q+1]);
                o2[4*q+2] = fmaf(hv, w.z, o2[4*q+2]);
                o2[4*q+3] = fmaf(hv, w.w, o2[4*q+3]);
            }
        }
        if (dir == 0) {
            #pragma unroll
            for (int j = 0; j < 32; j++) o[j] = fmaxf(o2[j], 0.f);
        } else {
            #pragma unroll
            for (int j = 0; j < 32; j++) o[j] = 0.5f * (o[j] + fmaxf(o2[j], 0.f));
        }
    }

    // round once to bf16; stats accumulate the ROUNDED value
    #pragma unroll
    for (int j = 0; j < 32; j++) o[j] = bf2f(f2bf(o[j]));

    if (valid) {
        uint4* op = (uint4*)(out + node * 32);
        #pragma unroll
        for (int q = 0; q < 4; q++) {
            uint4 u;
            u.x = (unsigned int)f2bf(o[8*q+0]) | ((unsigned int)f2bf(o[8*q+1]) << 16);
            u.y = (unsigned int)f2bf(o[8*q+2]) | ((unsigned int)f2bf(o[8*q+3]) << 16);
            u.z = (unsigned int)f2bf(o[8*q+4]) | ((unsigned int)f2bf(o[8*q+5]) << 16);
            u.w = (unsigned int)f2bf(o[8*q+6]) | ((unsigned int)f2bf(o[8*q+7]) << 16);
            op[q] = u;
        }
    }

    int lane = tid & 63;
    int wave = tid >> 6;
    #pragma unroll
    for (int f = 0; f < 32; f++) {
        float v = valid ? o[f] : 0.f;
        float v2 = v * v;
        #pragma unroll
        for (int offs = 32; offs > 0; offs >>= 1) {
            v  += __shfl_down(v, offs);
            v2 += __shfl_down(v2, offs);
        }
        if (lane == 0) {
            sred[wave * 64 + f]      = v;
            sred[wave * 64 + 32 + f] = v2;
        }
    }
    __syncthreads();
    if (tid < 64) {
        float a = sred[tid] + sred[64 + tid] + sred[128 + tid] + sred[192 + tid];
        atomicAdd(&stats[tid], a);
    }
}

// ================= segmented mean-pool (batch is sorted) + head =============

__global__ void pool_seg(const unsigned short* __restrict__ h, const int* __restrict__ batch,
                         float* __restrict__ psum, float* __restrict__ pcnt, int n)
{
    int tid = threadIdx.x;
    int grp = tid >> 5, f = tid & 31;
    int base = blockIdx.x * 256;
    float acc = 0.f, cnt = 0.f;
    int curg = -1;
    for (int it = 0; it < 32; it++) {
        int nd = base + grp + it * 8;
        if (nd < n) {
            int g = batch[nd];
            if (g != curg) {
                if (curg >= 0) {
                    atomicAdd(&psum[curg * 32 + f], acc);
                    if (f == 0) atomicAdd(&pcnt[curg], cnt);
                }
                curg = g; acc = 0.f; cnt = 0.f;
            }
            acc += bf2f(h[nd * 32 + f]);
            cnt += 1.f;
        }
    }
    if (curg >= 0) {
        atomicAdd(&psum[curg * 32 + f], acc);
        if (f == 0) atomicAdd(&pcnt[curg], cnt);
    }
}

__global__ void head_kernel(const float* __restrict__ psum, const float* __restrict__ pcnt,
                            const float* __restrict__ stats3,
                            const float* __restrict__ g3, const float* __restrict__ b3,
                            const float* __restrict__ lbW, const float* __restrict__ lbb,
                            const float* __restrict__ lmW, const float* __restrict__ lmb,
                            float* __restrict__ out)
{
    int g = threadIdx.x;  // 512 threads, one block
    float cnt = fmaxf(pcnt[g], 1.0f);
    float inv = 1.0f / cnt;
    float p[32];
    #pragma unroll
    for (int i = 0; i < 32; i++) {
        float mu  = stats3[i] * INV_N;
        float var = stats3[32 + i] * INV_N - mu * mu;
        float a   = g3[i] * rsqrtf(var + BN_EPS);
        float b   = b3[i] - mu * a;
        p[i] = fmaf(a, psum[g * 32 + i] * inv, b);
    }
    float z = lmb[0];
    #pragma unroll
    for (int k = 0; k < 16; k++) {
        float acc = lbb[k];
        #pragma unroll
        for (int i = 0; i < 32; i++) acc += p[i] * lbW[i * 16 + k];
        z += fmaxf(acc, 0.0f) * lmW[k];
    }
    out[g] = 1.0f / (1.0f + expf(-z));
}

// ================= launcher =================================================

extern "C" void kernel_launch(void* const* d_in, const int* in_sizes, int n_in,
                              void* d_out, int out_size, void* d_ws, size_t ws_size,
                              hipStream_t stream)
{
    const float* x   = (const float*)d_in[0];
    const int* ei    = (const int*)d_in[1];
    const int* batch = (const int*)d_in[2];
    const int* src = ei;
    const int* dst = ei + N_EDGES;
    char* ws = (char*)d_ws;

    auto W = [&](int l, int j) { return (const float*)d_in[3 + (l - 1) * 10 + j]; };

    // ---------------- layout ----------------
    unsigned short* h = (unsigned short*)(ws + 0);   // 16 MB (bf16 N x 32)
    float* agg  = (float*)(ws + 32000000);     // 64 MB (N x 64 fp32, interleaved F|B)
    int*   eidx = (int*)  (ws + 96000000);     // 20 MB
    int*   off  = (int*)  (ws + 116000000);    // (NT+1) ints
    // CSR-build temps live inside the agg region (dead until first gather)
    int*   deg   = (int*)  (ws + 32000000);    // 2 MB
    int*   excl  = (int*)  (ws + 34000016);    // 2 MB
    int*   bsum  = (int*)  (ws + 36000016);    // ~2 KB
    int*   boff  = (int*)  (ws + 36004016);    // ~2 KB
    int*   rank  = (int*)  (ws + 38000016);    // 10 MB packed rF|rB<<16
    float* stats1 = (float*)(ws + 118000016);
    float* stats2 = stats1 + 64;
    float* stats3 = stats1 + 128;
    float* psum   = (float*)(ws + 118000784);
    float* pcnt   = (float*)(ws + 118066320);

    // ---- CSR build: rank pass (atomics) -> scan -> atomic-free fill
    hipMemsetAsync(deg, 0, NT * 4, stream);
    k_rank<<<(N_EDGES + 255) / 256, 256, 0, stream>>>(src, dst, deg, rank, N_EDGES);
    int nb = (NT + 1023) / 1024;
    scan1<<<nb, 256, 0, stream>>>(deg, excl, bsum, NT);
    scan2<<<1, 512, 0, stream>>>(bsum, boff, nb);
    scan3<<<(NT + 256) / 256, 256, 0, stream>>>(excl, boff, off, NT);
    k_fill2<<<(N_EDGES + 255) / 256, 256, 0, stream>>>(src, dst, off, rank, eidx, N_EDGES);

    hipMemsetAsync(stats1, 0, 3 * 64 * 4, stream);

    const int GG = 4096;
    const int NG = N_NODES / 8;             // 31250 gather groups
    const int GM = (N_NODES + 255) / 256;   // 977 mlp blocks (thread-per-node)

    // layer 1 (DIN=6, fp32 x): x -> h (bf16), stats1
    gather_nbr<6, false><<<GG, 256, 0, stream>>>(x, off, eidx, agg, NG);
    dgin_mlp2<6, false, false><<<GM, 256, 0, stream>>>(
        x, agg, off, nullptr, nullptr, nullptr,
        W(1,0), W(1,1), W(1,2), W(1,3), W(1,4), W(1,5), W(1,6), W(1,7),
        h, stats1, N_NODES);

    // layer 2: h (bf16) -> h (in place), stats2
    gather_nbr<32, true><<<GG, 256, 0, stream>>>(h, off, eidx, agg, NG);
    dgin_mlp2<32, true, true><<<GM, 256, 0, stream>>>(
        h, agg, off, stats1, W(1,8), W(1,9),
        W(2,0), W(2,1), W(2,2), W(2,3), W(2,4), W(2,5), W(2,6), W(2,7),
        h, stats2, N_NODES);

    // layer 3: h -> h (in place), stats3
    gather_nbr<32, true><<<GG, 256, 0, stream>>>(h, off, eidx, agg, NG);
    dgin_mlp2<32, true, true><<<GM, 256, 0, stream>>>(
        h, agg, off, stats2, W(2,8), W(2,9),
        W(3,0), W(3,1), W(3,2), W(3,3), W(3,4), W(3,5), W(3,6), W(3,7),
        h, stats3, N_NODES);

    hipMemsetAsync(psum, 0, (size_t)N_GRAPHS * 32 * 4, stream);
    hipMemsetAsync(pcnt, 0, (size_t)N_GRAPHS * 4, stream);
    pool_seg<<<(N_NODES + 255) / 256, 256, 0, stream>>>(h, batch, psum, pcnt, N_NODES);
    head_kernel<<<1, 512, 0, stream>>>(psum, pcnt, stats3, W(3,8), W(3,9),
        (const float*)d_in[33], (const float*)d_in[34],
        (const float*)d_in[35], (const float*)d_in[36],
        (float*)d_out);
}

// Round 17
// 1177.405 us; speedup vs baseline: 1.8150x; 1.0170x over previous
//
#include <hip/hip_runtime.h>
#include <math.h>

#define N_NODES 250000
#define N_EDGES 2500000
#define N_GRAPHS 512
#define BN_EPS 1e-5f
#define NT 500000   // 2*N_NODES degree/offset slots (F then B)
#define INV_N (1.0f / (float)N_NODES)

// bf16 helpers (RNE); bf16->fp32 is an exact bit shift.
__device__ __forceinline__ unsigned short f2bf(float x) {
    unsigned int u = __float_as_uint(x);
    unsigned int r = (u + 0x7FFFu + ((u >> 16) & 1u)) >> 16;
    return (unsigned short)r;
}
__device__ __forceinline__ float bf2f(unsigned short b) {
    return __uint_as_float(((unsigned int)b) << 16);
}

// ================= CSR build (per call; ws is re-poisoned every launch) =====
// k_rank: computes degrees AND each edge's rank (atomicAdd return value),
// packed rankF|rankB<<16. k_fill2 places edges with ZERO atomics (R15 win).

__global__ void k_rank(const int* __restrict__ src, const int* __restrict__ dst,
                       int* __restrict__ deg, int* __restrict__ rank, int E)
{
    int e = blockIdx.x * blockDim.x + threadIdx.x;
    if (e >= E) return;
    int rF = atomicAdd(&deg[dst[e]], 1);            // F lists keyed by dst
    int rB = atomicAdd(&deg[N_NODES + src[e]], 1);  // B lists keyed by src
    rank[e] = rF | (rB << 16);
}

__global__ void k_fill2(const int* __restrict__ src, const int* __restrict__ dst,
                        const int* __restrict__ off, const int* __restrict__ rank,
                        int* __restrict__ eidx, int E)
{
    int e = blockIdx.x * blockDim.x + threadIdx.x;
    if (e >= E) return;
    int s = src[e], d = dst[e];
    int r = rank[e];
    eidx[off[d] + (r & 0xFFFF)] = s;
    eidx[off[N_NODES + s] + (r >> 16)] = d;
}

__global__ void scan1(const int* __restrict__ deg, int* __restrict__ excl,
                      int* __restrict__ bsum, int n)
{
    __shared__ int s[256];
    int t = threadIdx.x, b = blockIdx.x;
    int base = b * 1024 + t * 4;
    int v[4]; int tsum = 0;
    #pragma unroll
    for (int i = 0; i < 4; i++) { v[i] = (base + i < n) ? deg[base + i] : 0; tsum += v[i]; }
    s[t] = tsum; __syncthreads();
    for (int o = 1; o < 256; o <<= 1) {
        int x = (t >= o) ? s[t - o] : 0; __syncthreads();
        s[t] += x; __syncthreads();
    }
    int run = s[t] - tsum;
    #pragma unroll
    for (int i = 0; i < 4; i++) { if (base + i < n) excl[base + i] = run; run += v[i]; }
    if (t == 255) bsum[b] = s[255];
}

__global__ void scan2(const int* __restrict__ bsum, int* __restrict__ boff, int nb)
{
    __shared__ int s[512];
    int t = threadIdx.x;
    int v = (t < nb) ? bsum[t] : 0;
    s[t] = v; __syncthreads();
    for (int o = 1; o < 512; o <<= 1) {
        int x = (t >= o) ? s[t - o] : 0; __syncthreads();
        s[t] += x; __syncthreads();
    }
    if (t < nb) boff[t] = s[t] - v;
}

__global__ void scan3(const int* __restrict__ excl, const int* __restrict__ boff,
                      int* __restrict__ off, int n)
{
    int i = blockIdx.x * blockDim.x + threadIdx.x;
    if (i < n) off[i] = excl[i] + boff[i >> 10];
    if (i == 0) off[n] = 2 * N_EDGES;
}

// ================= layer-1 gather (fp32 x, DIN=6): lane-per-feature =========

__global__ __launch_bounds__(256, 4)
void gather_nbr6(const float* __restrict__ xf, const int* __restrict__ off,
                 const int* __restrict__ eidx, float* __restrict__ agg, int ngroups)
{
    int tid = threadIdx.x;
    int f = tid & 31, hw = tid >> 5;
    for (int grp = blockIdx.x; grp < ngroups; grp += gridDim.x) {
        int node = grp * 8 + hw;
        #pragma unroll
        for (int dir = 0; dir < 2; dir++) {
            int u = dir * N_NODES + node;
            int k0 = off[u], k1 = off[u + 1];
            float r0 = 0.f, r1 = 0.f, r2 = 0.f, r3 = 0.f;
            for (int p = k0; p < k1; p += 8) {
                #pragma unroll
                for (int q = 0; q < 8; q++) {
                    int kk = p + q;
                    bool act = (kk < k1);
                    int j = eidx[act ? kk : k0];
                    float v = (f < 6) ? xf[j * 6 + f] : 0.f;
                    v = act ? v : 0.f;
                    if ((q & 3) == 0)      r0 += v;
                    else if ((q & 3) == 1) r1 += v;
                    else if ((q & 3) == 2) r2 += v;
                    else                   r3 += v;
                }
            }
            float s = (r0 + r1) + (r2 + r3);
            if (f < 6) agg[node * 12 + dir * 6 + f] = s;
        }
    }
}

// ================= bf16 gather (DIN=32): ushort2 per lane, 16 lanes/row =====
// R16 gather was issue-bound (occ 81%, VALU 35%, neither pipe saturated):
// 32 lanes x 2B per row wastes issue slots. 16 lanes x uint (2 bf16) per row
// -> a wave serves 4 rows per load instruction, halving per-edge load+VALU
// counts; same 8-deep miss queue per chain. VGPR ~20 -> (256,8) cap 32.

__global__ __launch_bounds__(256, 8)
void gather16(const unsigned short* __restrict__ xb, const int* __restrict__ off,
              const int* __restrict__ eidx, float* __restrict__ agg, int ngroups)
{
    const unsigned int* xu = (const unsigned int*)xb;   // row = 16 uints
    int tid = threadIdx.x;
    int fp = tid & 15;          // feature pair: features 2fp, 2fp+1
    int gg = tid >> 4;          // group in block, 0..15
    for (int grp = blockIdx.x; grp < ngroups; grp += gridDim.x) {
        int node = grp * 16 + gg;
        #pragma unroll
        for (int dir = 0; dir < 2; dir++) {
            int u = dir * N_NODES + node;
            int k0 = off[u], k1 = off[u + 1];
            float a0 = 0.f, a1 = 0.f, b0 = 0.f, b1 = 0.f;
            float c0 = 0.f, c1 = 0.f, d0 = 0.f, d1 = 0.f;
            for (int p = k0; p < k1; p += 8) {
                #pragma unroll
                for (int q = 0; q < 8; q++) {
                    int kk = p + q;
                    bool act = (kk < k1);
                    int j = eidx[act ? kk : k0];
                    unsigned int v = xu[j * 16 + fp];
                    float lo = act ? __uint_as_float(v << 16) : 0.f;
                    float hi = act ? __uint_as_float(v & 0xFFFF0000u) : 0.f;
                    if ((q & 3) == 0)      { a0 += lo; a1 += hi; }
                    else if ((q & 3) == 1) { b0 += lo; b1 += hi; }
                    else if ((q & 3) == 2) { c0 += lo; c1 += hi; }
                    else                   { d0 += lo; d1 += hi; }
                }
            }
            float2 s;
            s.x = (a0 + b0) + (c0 + d0);
            s.y = (a1 + b1) + (c1 + d1);
            *(float2*)(agg + node * 64 + dir * 32 + 2 * fp) = s;
        }
    }
}

// ================= thread-per-node dual-direction GIN MLP + BN stats ========
// R14 win: broadcast ds_read_b128 weights, zero shfls. (256,1) -> 256-VGPR
// cap, no spill. Output h bf16; stats accumulate the ROUNDED values so the
// next layer's folded BN is self-consistent:
//   sum over (deg+1) rows of (a*v+b) = a*raw_sum + (deg+1)*b.

template <int DIN, bool BN_IN, bool IN_BF16>
__global__ __launch_bounds__(256, 1)
void dgin_mlp2(const void* __restrict__ xin_v, const float* __restrict__ agg,
               const int* __restrict__ off,
               const float* __restrict__ in_stats,
               const float* __restrict__ in_g, const float* __restrict__ in_b,
               const float* __restrict__ W1f, const float* __restrict__ b1f,
               const float* __restrict__ W2f, const float* __restrict__ b2f,
               const float* __restrict__ W1b, const float* __restrict__ b1b,
               const float* __restrict__ W2b, const float* __restrict__ b2b,
               unsigned short* __restrict__ out, float* __restrict__ stats, int n)
{
    const float* xf = (const float*)xin_v;
    const unsigned short* xb = (const unsigned short*)xin_v;

    __shared__ __align__(16) float sW1[2][DIN * 32];
    __shared__ __align__(16) float sW2[2][32 * 32];
    __shared__ float sb1[2][32], sb2[2][32];
    __shared__ float sscale[32], sshift[32];
    __shared__ float sred[4 * 64];

    int tid = threadIdx.x;
    for (int i = tid; i < DIN * 32; i += 256) { sW1[0][i] = W1f[i]; sW1[1][i] = W1b[i]; }
    for (int i = tid; i < 32 * 32;  i += 256) { sW2[0][i] = W2f[i]; sW2[1][i] = W2b[i]; }
    if (tid < 32) {
        sb1[0][tid] = b1f[tid]; sb1[1][tid] = b1b[tid];
        sb2[0][tid] = b2f[tid]; sb2[1][tid] = b2b[tid];
        if (BN_IN) {
            float mu  = in_stats[tid] * INV_N;
            float var = in_stats[32 + tid] * INV_N - mu * mu;
            float sc  = in_g[tid] * rsqrtf(var + BN_EPS);
            sscale[tid] = sc;
            sshift[tid] = in_b[tid] - mu * sc;
        } else { sscale[tid] = 1.f; sshift[tid] = 0.f; }
    }
    __syncthreads();

    int n0 = blockIdx.x * 256 + tid;
    bool valid = (n0 < n);
    int node = valid ? n0 : (n - 1);

    // self row
    float xr[DIN];
    if (IN_BF16) {
        const uint4* xp = (const uint4*)(xb + node * 32);
        #pragma unroll
        for (int q = 0; q < 4; q++) {
            uint4 u = xp[q];
            unsigned int w[4] = {u.x, u.y, u.z, u.w};
            #pragma unroll
            for (int k = 0; k < 4; k++) {
                xr[8*q + 2*k]     = __uint_as_float(w[k] << 16);
                xr[8*q + 2*k + 1] = __uint_as_float(w[k] & 0xFFFF0000u);
            }
        }
    } else if (DIN == 32) {
        const float4* xp = (const float4*)(xf + node * 32);
        #pragma unroll
        for (int q = 0; q < 8; q++) {
            float4 w = xp[q];
            xr[4*q+0] = w.x; xr[4*q+1] = w.y; xr[4*q+2] = w.z; xr[4*q+3] = w.w;
        }
    } else {
        const float2* xp = (const float2*)(xf + node * DIN);
        #pragma unroll
        for (int q = 0; q < DIN / 2; q++) {
            float2 w = xp[q];
            xr[2*q+0] = w.x; xr[2*q+1] = w.y;
        }
    }

    float o[32];

    #pragma unroll
    for (int dir = 0; dir < 2; dir++) {
        float ag[DIN];
        if (DIN == 32) {
            const float4* ap = (const float4*)(agg + node * 64 + dir * 32);
            #pragma unroll
            for (int q = 0; q < 8; q++) {
                float4 w = ap[q];
                ag[4*q+0] = w.x; ag[4*q+1] = w.y; ag[4*q+2] = w.z; ag[4*q+3] = w.w;
            }
        } else {
            const float* ap = agg + node * (2 * DIN) + dir * DIN;
            #pragma unroll
            for (int i = 0; i < DIN; i++) ag[i] = ap[i];
        }
        int ob = dir * N_NODES + node;
        float degp1 = (float)(off[ob + 1] - off[ob] + 1);

        float t1[32];
        #pragma unroll
        for (int j = 0; j < 32; j++) t1[j] = sb1[dir][j];
        #pragma unroll
        for (int i = 0; i < DIN; i++) {
            float hv = xr[i] + ag[i];
            if (BN_IN) hv = fmaf(sscale[i], hv, degp1 * sshift[i]);
            const float4* wr = (const float4*)(&sW1[dir][i * 32]);
            #pragma unroll
            for (int q = 0; q < 8; q++) {
                float4 w = wr[q];
                t1[4*q+0] = fmaf(hv, w.x, t1[4*q+0]);
                t1[4*q+1] = fmaf(hv, w.y, t1[4*q+1]);
                t1[4*q+2] = fmaf(hv, w.z, t1[4*q+2]);
                t1[4*q+3] = fmaf(hv, w.w, t1[4*q+3]);
            }
        }
        #pragma unroll
        for (int j = 0; j < 32; j++) t1[j] = fmaxf(t1[j], 0.f);

        float o2[32];
        #pragma unroll
        for (int j = 0; j < 32; j++) o2[j] = sb2[dir][j];
        #pragma unroll
        for (int i = 0; i < 32; i++) {
            float hv = t1[i];
            const float4* wr = (const float4*)(&sW2[dir][i * 32]);
            #pragma unroll
            for (int q = 0; q < 8; q++) {
                float4 w = wr[q];
                o2[4*q+0] = fmaf(hv, w.x, o2[4*q+0]);
                o2[4*q+1] = fmaf(hv, w.y, o2[4*q+1]);
                o2[4*q+2] = fmaf(hv, w.z, o2[4*q+2]);
                o2[4*q+3] = fmaf(hv, w.w, o2[4*q+3]);
            }
        }
        if (dir == 0) {
            #pragma unroll
            for (int j = 0; j < 32; j++) o[j] = fmaxf(o2[j], 0.f);
        } else {
            #pragma unroll
            for (int j = 0; j < 32; j++) o[j] = 0.5f * (o[j] + fmaxf(o2[j], 0.f));
        }
    }

    // round once to bf16; stats accumulate the ROUNDED value
    #pragma unroll
    for (int j = 0; j < 32; j++) o[j] = bf2f(f2bf(o[j]));

    if (valid) {
        uint4* op = (uint4*)(out + node * 32);
        #pragma unroll
        for (int q = 0; q < 4; q++) {
            uint4 u;
            u.x = (unsigned int)f2bf(o[8*q+0]) | ((unsigned int)f2bf(o[8*q+1]) << 16);
            u.y = (unsigned int)f2bf(o[8*q+2]) | ((unsigned int)f2bf(o[8*q+3]) << 16);
            u.z = (unsigned int)f2bf(o[8*q+4]) | ((unsigned int)f2bf(o[8*q+5]) << 16);
            u.w = (unsigned int)f2bf(o[8*q+6]) | ((unsigned int)f2bf(o[8*q+7]) << 16);
            op[q] = u;
        }
    }

    int lane = tid & 63;
    int wave = tid >> 6;
    #pragma unroll
    for (int f = 0; f < 32; f++) {
        float v = valid ? o[f] : 0.f;
        float v2 = v * v;
        #pragma unroll
        for (int offs = 32; offs > 0; offs >>= 1) {
            v  += __shfl_down(v, offs);
            v2 += __shfl_down(v2, offs);
        }
        if (lane == 0) {
            sred[wave * 64 + f]      = v;
            sred[wave * 64 + 32 + f] = v2;
        }
    }
    __syncthreads();
    if (tid < 64) {
        float a = sred[tid] + sred[64 + tid] + sred[128 + tid] + sred[192 + tid];
        atomicAdd(&stats[tid], a);
    }
}

// ================= segmented mean-pool (batch is sorted) + head =============

__global__ void pool_seg(const unsigned short* __restrict__ h, const int* __restrict__ batch,
                         float* __restrict__ psum, float* __restrict__ pcnt, int n)
{
    int tid = threadIdx.x;
    int grp = tid >> 5, f = tid & 31;
    int base = blockIdx.x * 256;
    float acc = 0.f, cnt = 0.f;
    int curg = -1;
    for (int it = 0; it < 32; it++) {
        int nd = base + grp + it * 8;
        if (nd < n) {
            int g = batch[nd];
            if (g != curg) {
                if (curg >= 0) {
                    atomicAdd(&psum[curg * 32 + f], acc);
                    if (f == 0) atomicAdd(&pcnt[curg], cnt);
                }
                curg = g; acc = 0.f; cnt = 0.f;
            }
            acc += bf2f(h[nd * 32 + f]);
            cnt += 1.f;
        }
    }
    if (curg >= 0) {
        atomicAdd(&psum[curg * 32 + f], acc);
        if (f == 0) atomicAdd(&pcnt[curg], cnt);
    }
}

__global__ void head_kernel(const float* __restrict__ psum, const float* __restrict__ pcnt,
                            const float* __restrict__ stats3,
                            const float* __restrict__ g3, const float* __restrict__ b3,
                            const float* __restrict__ lbW, const float* __restrict__ lbb,
                            const float* __restrict__ lmW, const float* __restrict__ lmb,
                            float* __restrict__ out)
{
    int g = threadIdx.x;  // 512 threads, one block
    float cnt = fmaxf(pcnt[g], 1.0f);
    float inv = 1.0f / cnt;
    float p[32];
    #pragma unroll
    for (int i = 0; i < 32; i++) {
        float mu  = stats3[i] * INV_N;
        float var = stats3[32 + i] * INV_N - mu * mu;
        float a   = g3[i] * rsqrtf(var + BN_EPS);
        float b   = b3[i] - mu * a;
        p[i] = fmaf(a, psum[g * 32 + i] * inv, b);
    }
    float z = lmb[0];
    #pragma unroll
    for (int k = 0; k < 16; k++) {
        float acc = lbb[k];
        #pragma unroll
        for (int i = 0; i < 32; i++) acc += p[i] * lbW[i * 16 + k];
        z += fmaxf(acc, 0.0f) * lmW[k];
    }
    out[g] = 1.0f / (1.0f + expf(-z));
}

// ================= launcher =================================================

extern "C" void kernel_launch(void* const* d_in, const int* in_sizes, int n_in,
                              void* d_out, int out_size, void* d_ws, size_t ws_size,
                              hipStream_t stream)
{
    const float* x   = (const float*)d_in[0];
    const int* ei    = (const int*)d_in[1];
    const int* batch = (const int*)d_in[2];
    const int* src = ei;
    const int* dst = ei + N_EDGES;
    char* ws = (char*)d_ws;

    auto W = [&](int l, int j) { return (const float*)d_in[3 + (l - 1) * 10 + j]; };

    // ---------------- layout ----------------
    unsigned short* h = (unsigned short*)(ws + 0);   // 16 MB (bf16 N x 32)
    float* agg  = (float*)(ws + 32000000);     // 64 MB (N x 64 fp32, interleaved F|B)
    int*   eidx = (int*)  (ws + 96000000);     // 20 MB
    int*   off  = (int*)  (ws + 116000000);    // (NT+1) ints
    // CSR-build temps live inside the agg region (dead until first gather)
    int*   deg   = (int*)  (ws + 32000000);    // 2 MB
    int*   excl  = (int*)  (ws + 34000016);    // 2 MB
    int*   bsum  = (int*)  (ws + 36000016);    // ~2 KB
    int*   boff  = (int*)  (ws + 36004016);    // ~2 KB
    int*   rank  = (int*)  (ws + 38000016);    // 10 MB packed rF|rB<<16
    float* stats1 = (float*)(ws + 118000016);
    float* stats2 = stats1 + 64;
    float* stats3 = stats1 + 128;
    float* psum   = (float*)(ws + 118000784);
    float* pcnt   = (float*)(ws + 118066320);

    // ---- CSR build: rank pass (atomics) -> scan -> atomic-free fill
    hipMemsetAsync(deg, 0, NT * 4, stream);
    k_rank<<<(N_EDGES + 255) / 256, 256, 0, stream>>>(src, dst, deg, rank, N_EDGES);
    int nb = (NT + 1023) / 1024;
    scan1<<<nb, 256, 0, stream>>>(deg, excl, bsum, NT);
    scan2<<<1, 512, 0, stream>>>(bsum, boff, nb);
    scan3<<<(NT + 256) / 256, 256, 0, stream>>>(excl, boff, off, NT);
    k_fill2<<<(N_EDGES + 255) / 256, 256, 0, stream>>>(src, dst, off, rank, eidx, N_EDGES);

    hipMemsetAsync(stats1, 0, 3 * 64 * 4, stream);

    const int GG  = 4096;
    const int NG8  = N_NODES / 8;            // 31250 groups (layer-1 gather)
    const int NG16 = N_NODES / 16;           // 15625 groups (bf16 gather16)
    const int GM  = (N_NODES + 255) / 256;   // 977 mlp blocks (thread-per-node)

    // layer 1 (DIN=6, fp32 x): x -> h (bf16), stats1
    gather_nbr6<<<GG, 256, 0, stream>>>(x, off, eidx, agg, NG8);
    dgin_mlp2<6, false, false><<<GM, 256, 0, stream>>>(
        x, agg, off, nullptr, nullptr, nullptr,
        W(1,0), W(1,1), W(1,2), W(1,3), W(1,4), W(1,5), W(1,6), W(1,7),
        h, stats1, N_NODES);

    // layer 2: h (bf16) -> h (in place), stats2
    gather16<<<GG, 256, 0, stream>>>(h, off, eidx, agg, NG16);
    dgin_mlp2<32, true, true><<<GM, 256, 0, stream>>>(
        h, agg, off, stats1, W(1,8), W(1,9),
        W(2,0), W(2,1), W(2,2), W(2,3), W(2,4), W(2,5), W(2,6), W(2,7),
        h, stats2, N_NODES);

    // layer 3: h -> h (in place), stats3
    gather16<<<GG, 256, 0, stream>>>(h, off, eidx, agg, NG16);
    dgin_mlp2<32, true, true><<<GM, 256, 0, stream>>>(
        h, agg, off, stats2, W(2,8), W(2,9),
        W(3,0), W(3,1), W(3,2), W(3,3), W(3,4), W(3,5), W(3,6), W(3,7),
        h, stats3, N_NODES);

    hipMemsetAsync(psum, 0, (size_t)N_GRAPHS * 32 * 4, stream);
    hipMemsetAsync(pcnt, 0, (size_t)N_GRAPHS * 4, stream);
    pool_seg<<<(N_NODES + 255) / 256, 256, 0, stream>>>(h, batch, psum, pcnt, N_NODES);
    head_kernel<<<1, 512, 0, stream>>>(psum, pcnt, stats3, W(3,8), W(3,9),
        (const float*)d_in[33], (const float*)d_in[34],
        (const float*)d_in[35], (const float*)d_in[36],
        (float*)d_out);
}

// Round 18
// 1052.554 us; speedup vs baseline: 2.0303x; 1.1186x over previous
//
#include <hip/hip_runtime.h>
#include <math.h>

#define N_NODES 250000
#define N_EDGES 2500000
#define N_GRAPHS 512
#define BN_EPS 1e-5f
#define NT 500000   // 2*N_NODES degree/offset slots (F then B)
#define INV_N (1.0f / (float)N_NODES)

// bf16 helpers (RNE); bf16->fp32 is an exact bit shift.
__device__ __forceinline__ unsigned short f2bf(float x) {
    unsigned int u = __float_as_uint(x);
    unsigned int r = (u + 0x7FFFu + ((u >> 16) & 1u)) >> 16;
    return (unsigned short)r;
}
__device__ __forceinline__ float bf2f(unsigned short b) {
    return __uint_as_float(((unsigned int)b) << 16);
}

// ================= CSR build (per call; ws is re-poisoned every launch) =====

__global__ void k_rank(const int* __restrict__ src, const int* __restrict__ dst,
                       int* __restrict__ deg, int* __restrict__ rank, int E)
{
    int e = blockIdx.x * blockDim.x + threadIdx.x;
    if (e >= E) return;
    int rF = atomicAdd(&deg[dst[e]], 1);            // F lists keyed by dst
    int rB = atomicAdd(&deg[N_NODES + src[e]], 1);  // B lists keyed by src
    rank[e] = rF | (rB << 16);
}

__global__ void k_fill2(const int* __restrict__ src, const int* __restrict__ dst,
                        const int* __restrict__ off, const int* __restrict__ rank,
                        int* __restrict__ eidx, int E)
{
    int e = blockIdx.x * blockDim.x + threadIdx.x;
    if (e >= E) return;
    int s = src[e], d = dst[e];
    int r = rank[e];
    eidx[off[d] + (r & 0xFFFF)] = s;
    eidx[off[N_NODES + s] + (r >> 16)] = d;
}

__global__ void scan1(const int* __restrict__ deg, int* __restrict__ excl,
                      int* __restrict__ bsum, int n)
{
    __shared__ int s[256];
    int t = threadIdx.x, b = blockIdx.x;
    int base = b * 1024 + t * 4;
    int v[4]; int tsum = 0;
    #pragma unroll
    for (int i = 0; i < 4; i++) { v[i] = (base + i < n) ? deg[base + i] : 0; tsum += v[i]; }
    s[t] = tsum; __syncthreads();
    for (int o = 1; o < 256; o <<= 1) {
        int x = (t >= o) ? s[t - o] : 0; __syncthreads();
        s[t] += x; __syncthreads();
    }
    int run = s[t] - tsum;
    #pragma unroll
    for (int i = 0; i < 4; i++) { if (base + i < n) excl[base + i] = run; run += v[i]; }
    if (t == 255) bsum[b] = s[255];
}

__global__ void scan2(const int* __restrict__ bsum, int* __restrict__ boff, int nb)
{
    __shared__ int s[512];
    int t = threadIdx.x;
    int v = (t < nb) ? bsum[t] : 0;
    s[t] = v; __syncthreads();
    for (int o = 1; o < 512; o <<= 1) {
        int x = (t >= o) ? s[t - o] : 0; __syncthreads();
        s[t] += x; __syncthreads();
    }
    if (t < nb) boff[t] = s[t] - v;
}

__global__ void scan3(const int* __restrict__ excl, const int* __restrict__ boff,
                      int* __restrict__ off, int n)
{
    int i = blockIdx.x * blockDim.x + threadIdx.x;
    if (i < n) off[i] = excl[i] + boff[i >> 10];
    if (i == 0) off[n] = 2 * N_EDGES;
}

// ================= pad x (N x 6 fp32) -> xpad (N x 8 fp32) ==================

__global__ void pad_x(const float* __restrict__ x, float* __restrict__ xpad, int n)
{
    int i = blockIdx.x * blockDim.x + threadIdx.x;   // one float2 out per thread
    if (i >= n * 4) return;
    int node = i >> 2, p2 = i & 3;
    float2 v;
    v.x = (2 * p2     < 6) ? x[node * 6 + 2 * p2]     : 0.f;
    v.y = (2 * p2 + 1 < 6) ? x[node * 6 + 2 * p2 + 1] : 0.f;
    *(float2*)(xpad + node * 8 + 2 * p2) = v;
}

// ============ layer-1 gather, PACKED: 4 lanes x float2 per padded row =======
// R17's gather_nbr6 wasted 26/32 lanes (rows are 6 floats). 4 lanes/row ->
// 16 rows per wave-instruction, 8x fewer issue slots. (256,8) cap 32; acc
// footprint ~24 VGPR (watch WRITE for spill).

__global__ __launch_bounds__(256, 8)
void gather6p(const float* __restrict__ xpad, const int* __restrict__ off,
              const int* __restrict__ eidx, float* __restrict__ agg, int ngroups)
{
    int tid = threadIdx.x;
    int p2   = tid & 3;       // float2 index within row (cols 2p2, 2p2+1)
    int slot = tid >> 2;      // 0..63 node slots per block
    for (int grp = blockIdx.x; grp < ngroups; grp += gridDim.x) {
        int node = grp * 64 + slot;
        bool nvalid = (node < N_NODES);
        int nd = nvalid ? node : 0;
        #pragma unroll
        for (int dir = 0; dir < 2; dir++) {
            int u = dir * N_NODES + nd;
            int k0 = off[u], k1 = off[u + 1];
            if (!nvalid) k1 = k0;
            float a0=0.f,a1=0.f,b0=0.f,b1=0.f,c0=0.f,c1=0.f,d0=0.f,d1=0.f;
            for (int p = k0; p < k1; p += 8) {
                #pragma unroll
                for (int q = 0; q < 8; q++) {
                    int kk = p + q;
                    bool act = (kk < k1);
                    int j = eidx[act ? kk : k0];
                    float2 v = *(const float2*)(xpad + j * 8 + 2 * p2);
                    float lo = act ? v.x : 0.f;
                    float hi = act ? v.y : 0.f;
                    if ((q & 3) == 0)      { a0 += lo; a1 += hi; }
                    else if ((q & 3) == 1) { b0 += lo; b1 += hi; }
                    else if ((q & 3) == 2) { c0 += lo; c1 += hi; }
                    else                   { d0 += lo; d1 += hi; }
                }
            }
            if (nvalid && p2 < 3) {
                float2 s;
                s.x = (a0 + b0) + (c0 + d0);
                s.y = (a1 + b1) + (c1 + d1);
                *(float2*)(agg + nd * 12 + dir * 6 + 2 * p2) = s;
            }
        }
    }
}

// ================= bf16 gather (DIN=32): ushort2 per lane, 16 lanes/row =====
// 8-deep queue, (256,8). Layer-2 variant (A of the A/B).

__global__ __launch_bounds__(256, 8)
void gather16(const unsigned short* __restrict__ xb, const int* __restrict__ off,
              const int* __restrict__ eidx, float* __restrict__ agg, int ngroups)
{
    const unsigned int* xu = (const unsigned int*)xb;   // row = 16 uints
    int tid = threadIdx.x;
    int fp = tid & 15;
    int gg = tid >> 4;
    for (int grp = blockIdx.x; grp < ngroups; grp += gridDim.x) {
        int node = grp * 16 + gg;
        #pragma unroll
        for (int dir = 0; dir < 2; dir++) {
            int u = dir * N_NODES + node;
            int k0 = off[u], k1 = off[u + 1];
            float a0 = 0.f, a1 = 0.f, b0 = 0.f, b1 = 0.f;
            float c0 = 0.f, c1 = 0.f, d0 = 0.f, d1 = 0.f;
            for (int p = k0; p < k1; p += 8) {
                #pragma unroll
                for (int q = 0; q < 8; q++) {
                    int kk = p + q;
                    bool act = (kk < k1);
                    int j = eidx[act ? kk : k0];
                    unsigned int v = xu[j * 16 + fp];
                    float lo = act ? __uint_as_float(v << 16) : 0.f;
                    float hi = act ? __uint_as_float(v & 0xFFFF0000u) : 0.f;
                    if ((q & 3) == 0)      { a0 += lo; a1 += hi; }
                    else if ((q & 3) == 1) { b0 += lo; b1 += hi; }
                    else if ((q & 3) == 2) { c0 += lo; c1 += hi; }
                    else                   { d0 += lo; d1 += hi; }
                }
            }
            float2 s;
            s.x = (a0 + b0) + (c0 + d0);
            s.y = (a1 + b1) + (c1 + d1);
            *(float2*)(agg + node * 64 + dir * 32 + 2 * fp) = s;
        }
    }
}

// 12-deep queue variant, (256,6) cap 42 (B of the A/B: does miss-queue depth
// matter, or is the gather at the L2/L3 random-row service floor?).

__global__ __launch_bounds__(256, 6)
void gather16_12(const unsigned short* __restrict__ xb, const int* __restrict__ off,
                 const int* __restrict__ eidx, float* __restrict__ agg, int ngroups)
{
    const unsigned int* xu = (const unsigned int*)xb;
    int tid = threadIdx.x;
    int fp = tid & 15;
    int gg = tid >> 4;
    for (int grp = blockIdx.x; grp < ngroups; grp += gridDim.x) {
        int node = grp * 16 + gg;
        #pragma unroll
        for (int dir = 0; dir < 2; dir++) {
            int u = dir * N_NODES + node;
            int k0 = off[u], k1 = off[u + 1];
            float a0 = 0.f, a1 = 0.f, b0 = 0.f, b1 = 0.f;
            float c0 = 0.f, c1 = 0.f, d0 = 0.f, d1 = 0.f;
            for (int p = k0; p < k1; p += 12) {
                #pragma unroll
                for (int q = 0; q < 12; q++) {
                    int kk = p + q;
                    bool act = (kk < k1);
                    int j = eidx[act ? kk : k0];
                    unsigned int v = xu[j * 16 + fp];
                    float lo = act ? __uint_as_float(v << 16) : 0.f;
                    float hi = act ? __uint_as_float(v & 0xFFFF0000u) : 0.f;
                    if ((q & 3) == 0)      { a0 += lo; a1 += hi; }
                    else if ((q & 3) == 1) { b0 += lo; b1 += hi; }
                    else if ((q & 3) == 2) { c0 += lo; c1 += hi; }
                    else                   { d0 += lo; d1 += hi; }
                }
            }
            float2 s;
            s.x = (a0 + b0) + (c0 + d0);
            s.y = (a1 + b1) + (c1 + d1);
            *(float2*)(agg + node * 64 + dir * 32 + 2 * fp) = s;
        }
    }
}

// ================= thread-per-node dual-direction GIN MLP + BN stats ========

template <int DIN, bool BN_IN, bool IN_BF16>
__global__ __launch_bounds__(256, 1)
void dgin_mlp2(const void* __restrict__ xin_v, const float* __restrict__ agg,
               const int* __restrict__ off,
               const float* __restrict__ in_stats,
               const float* __restrict__ in_g, const float* __restrict__ in_b,
               const float* __restrict__ W1f, const float* __restrict__ b1f,
               const float* __restrict__ W2f, const float* __restrict__ b2f,
               const float* __restrict__ W1b, const float* __restrict__ b1b,
               const float* __restrict__ W2b, const float* __restrict__ b2b,
               unsigned short* __restrict__ out, float* __restrict__ stats, int n)
{
    const float* xf = (const float*)xin_v;
    const unsigned short* xb = (const unsigned short*)xin_v;

    __shared__ __align__(16) float sW1[2][DIN * 32];
    __shared__ __align__(16) float sW2[2][32 * 32];
    __shared__ float sb1[2][32], sb2[2][32];
    __shared__ float sscale[32], sshift[32];
    __shared__ float sred[4 * 64];

    int tid = threadIdx.x;
    for (int i = tid; i < DIN * 32; i += 256) { sW1[0][i] = W1f[i]; sW1[1][i] = W1b[i]; }
    for (int i = tid; i < 32 * 32;  i += 256) { sW2[0][i] = W2f[i]; sW2[1][i] = W2b[i]; }
    if (tid < 32) {
        sb1[0][tid] = b1f[tid]; sb1[1][tid] = b1b[tid];
        sb2[0][tid] = b2f[tid]; sb2[1][tid] = b2b[tid];
        if (BN_IN) {
            float mu  = in_stats[tid] * INV_N;
            float var = in_stats[32 + tid] * INV_N - mu * mu;
            float sc  = in_g[tid] * rsqrtf(var + BN_EPS);
            sscale[tid] = sc;
            sshift[tid] = in_b[tid] - mu * sc;
        } else { sscale[tid] = 1.f; sshift[tid] = 0.f; }
    }
    __syncthreads();

    int n0 = blockIdx.x * 256 + tid;
    bool valid = (n0 < n);
    int node = valid ? n0 : (n - 1);

    // self row
    float xr[DIN];
    if (IN_BF16) {
        const uint4* xp = (const uint4*)(xb + node * 32);
        #pragma unroll
        for (int q = 0; q < 4; q++) {
            uint4 u = xp[q];
            unsigned int w[4] = {u.x, u.y, u.z, u.w};
            #pragma unroll
            for (int k = 0; k < 4; k++) {
                xr[8*q + 2*k]     = __uint_as_float(w[k] << 16);
                xr[8*q + 2*k + 1] = __uint_as_float(w[k] & 0xFFFF0000u);
            }
        }
    } else if (DIN == 32) {
        const float4* xp = (const float4*)(xf + node * 32);
        #pragma unroll
        for (int q = 0; q < 8; q++) {
            float4 w = xp[q];
            xr[4*q+0] = w.x; xr[4*q+1] = w.y; xr[4*q+2] = w.z; xr[4*q+3] = w.w;
        }
    } else {
        const float2* xp = (const float2*)(xf + node * DIN);
        #pragma unroll
        for (int q = 0; q < DIN / 2; q++) {
            float2 w = xp[q];
            xr[2*q+0] = w.x; xr[2*q+1] = w.y;
        }
    }

    float o[32];

    #pragma unroll
    for (int dir = 0; dir < 2; dir++) {
        float ag[DIN];
        if (DIN == 32) {
            const float4* ap = (const float4*)(agg + node * 64 + dir * 32);
            #pragma unroll
            for (int q = 0; q < 8; q++) {
                float4 w = ap[q];
                ag[4*q+0] = w.x; ag[4*q+1] = w.y; ag[4*q+2] = w.z; ag[4*q+3] = w.w;
            }
        } else {
            const float* ap = agg + node * (2 * DIN) + dir * DIN;
            #pragma unroll
            for (int i = 0; i < DIN; i++) ag[i] = ap[i];
        }
        int ob = dir * N_NODES + node;
        float degp1 = (float)(off[ob + 1] - off[ob] + 1);

        float t1[32];
        #pragma unroll
        for (int j = 0; j < 32; j++) t1[j] = sb1[dir][j];
        #pragma unroll
        for (int i = 0; i < DIN; i++) {
            float hv = xr[i] + ag[i];
            if (BN_IN) hv = fmaf(sscale[i], hv, degp1 * sshift[i]);
            const float4* wr = (const float4*)(&sW1[dir][i * 32]);
            #pragma unroll
            for (int q = 0; q < 8; q++) {
                float4 w = wr[q];
                t1[4*q+0] = fmaf(hv, w.x, t1[4*q+0]);
                t1[4*q+1] = fmaf(hv, w.y, t1[4*q+1]);
                t1[4*q+2] = fmaf(hv, w.z, t1[4*q+2]);
                t1[4*q+3] = fmaf(hv, w.w, t1[4*q+3]);
            }
        }
        #pragma unroll
        for (int j = 0; j < 32; j++) t1[j] = fmaxf(t1[j], 0.f);

        float o2[32];
        #pragma unroll
        for (int j = 0; j < 32; j++) o2[j] = sb2[dir][j];
        #pragma unroll
        for (int i = 0; i < 32; i++) {
            float hv = t1[i];
            const float4* wr = (const float4*)(&sW2[dir][i * 32]);
            #pragma unroll
            for (int q = 0; q < 8; q++) {
                float4 w = wr[q];
                o2[4*q+0] = fmaf(hv, w.x, o2[4*q+0]);
                o2[4*q+1] = fmaf(hv, w.y, o2[4*q+1]);
                o2[4*q+2] = fmaf(hv, w.z, o2[4*q+2]);
                o2[4*q+3] = fmaf(hv, w.w, o2[4*q+3]);
            }
        }
        if (dir == 0) {
            #pragma unroll
            for (int j = 0; j < 32; j++) o[j] = fmaxf(o2[j], 0.f);
        } else {
            #pragma unroll
            for (int j = 0; j < 32; j++) o[j] = 0.5f * (o[j] + fmaxf(o2[j], 0.f));
        }
    }

    // round once to bf16; stats accumulate the ROUNDED value
    #pragma unroll
    for (int j = 0; j < 32; j++) o[j] = bf2f(f2bf(o[j]));

    if (valid) {
        uint4* op = (uint4*)(out + node * 32);
        #pragma unroll
        for (int q = 0; q < 4; q++) {
            uint4 u;
            u.x = (unsigned int)f2bf(o[8*q+0]) | ((unsigned int)f2bf(o[8*q+1]) << 16);
            u.y = (unsigned int)f2bf(o[8*q+2]) | ((unsigned int)f2bf(o[8*q+3]) << 16);
            u.z = (unsigned int)f2bf(o[8*q+4]) | ((unsigned int)f2bf(o[8*q+5]) << 16);
            u.w = (unsigned int)f2bf(o[8*q+6]) | ((unsigned int)f2bf(o[8*q+7]) << 16);
            op[q] = u;
        }
    }

    int lane = tid & 63;
    int wave = tid >> 6;
    #pragma unroll
    for (int f = 0; f < 32; f++) {
        float v = valid ? o[f] : 0.f;
        float v2 = v * v;
        #pragma unroll
        for (int offs = 32; offs > 0; offs >>= 1) {
            v  += __shfl_down(v, offs);
            v2 += __shfl_down(v2, offs);
        }
        if (lane == 0) {
            sred[wave * 64 + f]      = v;
            sred[wave * 64 + 32 + f] = v2;
        }
    }
    __syncthreads();
    if (tid < 64) {
        float a = sred[tid] + sred[64 + tid] + sred[128 + tid] + sred[192 + tid];
        atomicAdd(&stats[tid], a);
    }
}

// ================= segmented mean-pool (batch is sorted) + head =============

__global__ void pool_seg(const unsigned short* __restrict__ h, const int* __restrict__ batch,
                         float* __restrict__ psum, float* __restrict__ pcnt, int n)
{
    int tid = threadIdx.x;
    int grp = tid >> 5, f = tid & 31;
    int base = blockIdx.x * 256;
    float acc = 0.f, cnt = 0.f;
    int curg = -1;
    for (int it = 0; it < 32; it++) {
        int nd = base + grp + it * 8;
        if (nd < n) {
            int g = batch[nd];
            if (g != curg) {
                if (curg >= 0) {
                    atomicAdd(&psum[curg * 32 + f], acc);
                    if (f == 0) atomicAdd(&pcnt[curg], cnt);
                }
                curg = g; acc = 0.f; cnt = 0.f;
            }
            acc += bf2f(h[nd * 32 + f]);
            cnt += 1.f;
        }
    }
    if (curg >= 0) {
        atomicAdd(&psum[curg * 32 + f], acc);
        if (f == 0) atomicAdd(&pcnt[curg], cnt);
    }
}

__global__ void head_kernel(const float* __restrict__ psum, const float* __restrict__ pcnt,
                            const float* __restrict__ stats3,
                            const float* __restrict__ g3, const float* __restrict__ b3,
                            const float* __restrict__ lbW, const float* __restrict__ lbb,
                            const float* __restrict__ lmW, const float* __restrict__ lmb,
                            float* __restrict__ out)
{
    int g = threadIdx.x;  // 512 threads, one block
    float cnt = fmaxf(pcnt[g], 1.0f);
    float inv = 1.0f / cnt;
    float p[32];
    #pragma unroll
    for (int i = 0; i < 32; i++) {
        float mu  = stats3[i] * INV_N;
        float var = stats3[32 + i] * INV_N - mu * mu;
        float a   = g3[i] * rsqrtf(var + BN_EPS);
        float b   = b3[i] - mu * a;
        p[i] = fmaf(a, psum[g * 32 + i] * inv, b);
    }
    float z = lmb[0];
    #pragma unroll
    for (int k = 0; k < 16; k++) {
        float acc = lbb[k];
        #pragma unroll
        for (int i = 0; i < 32; i++) acc += p[i] * lbW[i * 16 + k];
        z += fmaxf(acc, 0.0f) * lmW[k];
    }
    out[g] = 1.0f / (1.0f + expf(-z));
}

// ================= launcher =================================================

extern "C" void kernel_launch(void* const* d_in, const int* in_sizes, int n_in,
                              void* d_out, int out_size, void* d_ws, size_t ws_size,
                              hipStream_t stream)
{
    const float* x   = (const float*)d_in[0];
    const int* ei    = (const int*)d_in[1];
    const int* batch = (const int*)d_in[2];
    const int* src = ei;
    const int* dst = ei + N_EDGES;
    char* ws = (char*)d_ws;

    auto W = [&](int l, int j) { return (const float*)d_in[3 + (l - 1) * 10 + j]; };

    // ---------------- layout ----------------
    unsigned short* h = (unsigned short*)(ws + 0);   // 16 MB (bf16 N x 32)
    float* xpad = (float*)(ws + 16000016);     // 8 MB (N x 8 fp32, padded x)
    float* agg  = (float*)(ws + 32000000);     // 64 MB (N x 64 fp32, interleaved F|B)
    int*   eidx = (int*)  (ws + 96000000);     // 20 MB
    int*   off  = (int*)  (ws + 116000000);    // (NT+1) ints
    // CSR-build temps live inside the agg region (dead until first gather)
    int*   deg   = (int*)  (ws + 32000000);    // 2 MB
    int*   excl  = (int*)  (ws + 34000016);    // 2 MB
    int*   bsum  = (int*)  (ws + 36000016);    // ~2 KB
    int*   boff  = (int*)  (ws + 36004016);    // ~2 KB
    int*   rank  = (int*)  (ws + 38000016);    // 10 MB packed rF|rB<<16
    float* stats1 = (float*)(ws + 118000016);
    float* stats2 = stats1 + 64;
    float* stats3 = stats1 + 128;
    float* psum   = (float*)(ws + 118000784);
    float* pcnt   = (float*)(ws + 118066320);

    // ---- CSR build: rank pass (atomics) -> scan -> atomic-free fill
    hipMemsetAsync(deg, 0, NT * 4, stream);
    k_rank<<<(N_EDGES + 255) / 256, 256, 0, stream>>>(src, dst, deg, rank, N_EDGES);
    int nb = (NT + 1023) / 1024;
    scan1<<<nb, 256, 0, stream>>>(deg, excl, bsum, NT);
    scan2<<<1, 512, 0, stream>>>(bsum, boff, nb);
    scan3<<<(NT + 256) / 256, 256, 0, stream>>>(excl, boff, off, NT);
    k_fill2<<<(N_EDGES + 255) / 256, 256, 0, stream>>>(src, dst, off, rank, eidx, N_EDGES);

    pad_x<<<(N_NODES * 4 + 255) / 256, 256, 0, stream>>>(x, xpad, N_NODES);
    hipMemsetAsync(stats1, 0, 3 * 64 * 4, stream);

    const int GG   = 4096;
    const int NG64 = (N_NODES + 63) / 64;    // 3907 groups (packed layer-1)
    const int NG16 = N_NODES / 16;           // 15625 groups (bf16 gather16)
    const int GM   = (N_NODES + 255) / 256;  // 977 mlp blocks (thread-per-node)

    // layer 1 (DIN=6): packed gather on xpad; mlp reads original fp32 x
    gather6p<<<GG, 256, 0, stream>>>(xpad, off, eidx, agg, NG64);
    dgin_mlp2<6, false, false><<<GM, 256, 0, stream>>>(
        x, agg, off, nullptr, nullptr, nullptr,
        W(1,0), W(1,1), W(1,2), W(1,3), W(1,4), W(1,5), W(1,6), W(1,7),
        h, stats1, N_NODES);

    // layer 2: 8-deep gather (A)
    gather16<<<GG, 256, 0, stream>>>(h, off, eidx, agg, NG16);
    dgin_mlp2<32, true, true><<<GM, 256, 0, stream>>>(
        h, agg, off, stats1, W(1,8), W(1,9),
        W(2,0), W(2,1), W(2,2), W(2,3), W(2,4), W(2,5), W(2,6), W(2,7),
        h, stats2, N_NODES);

    // layer 3: 12-deep gather (B) — within-round A/B vs layer 2
    gather16_12<<<GG, 256, 0, stream>>>(h, off, eidx, agg, NG16);
    dgin_mlp2<32, true, true><<<GM, 256, 0, stream>>>(
        h, agg, off, stats2, W(2,8), W(2,9),
        W(3,0), W(3,1), W(3,2), W(3,3), W(3,4), W(3,5), W(3,6), W(3,7),
        h, stats3, N_NODES);

    hipMemsetAsync(psum, 0, (size_t)N_GRAPHS * 32 * 4, stream);
    hipMemsetAsync(pcnt, 0, (size_t)N_GRAPHS * 4, stream);
    pool_seg<<<(N_NODES + 255) / 256, 256, 0, stream>>>(h, batch, psum, pcnt, N_NODES);
    head_kernel<<<1, 512, 0, stream>>>(psum, pcnt, stats3, W(3,8), W(3,9),
        (const float*)d_in[33], (const float*)d_in[34],
        (const float*)d_in[35], (const float*)d_in[36],
        (float*)d_out);
}